// Round 5
// baseline (470.267 us; speedup 1.0000x reference)
//
#include <hip/hip_runtime.h>
#include <hip/hip_bf16.h>

#define NN 50000
#define CIN 128
#define HH 4
#define DD 32
#define HD 128
#define EE 800000
#define ETOT (EE + NN)
#define NEG 0.2f

// ---------------------------------------------------------------------------
// ws layout (units of 4B):
//   [0]                  : flag (1 = edge_index is int64, 0 = int32)
//   [16 .. +1600000)     : ei32 (normalized int32 edge index, 2*EE)
//   XL_OFF  = 1600016    : xl (NN*128 f32)
//   XR_OFF  = 8000016    : xr
//   EB_OFF  = 14400016   : per-edge scores / exp (ETOT*4)
//   EMAX_OFF= 17800016   : per-(node,head) max (NN*4)
//   DEN_OFF = 18000016   : per-(node,head) denom (NN*4)
//   ACC_OFF = 18200016   : output accum (NN*32)
// total 19800016 elems = 79.2 MB
// ---------------------------------------------------------------------------
#define EI_OFF   16
#define XL_OFF   1600016
#define XR_OFF   8000016
#define EB_OFF   14400016
#define EMAX_OFF 17800016
#define DEN_OFF  18000016
#define ACC_OFF  18200016

// ---------------------------------------------------------------------------
// Detect int64 vs int32 edge_index: int64 values < 2^31 have zero odd words.
// ---------------------------------------------------------------------------
__global__ void detect_kernel(const int* __restrict__ ei_raw, int* __restrict__ flag)
{
    const int l = threadIdx.x;                // 64 threads
    const int w = ei_raw[2 * l + 1];
    const unsigned long long b = __ballot(w != 0);
    if (l == 0) flag[0] = (b == 0ULL) ? 1 : 0;
}

__global__ __launch_bounds__(256) void convert_ei_kernel(
    const int* __restrict__ ei_raw, const int* __restrict__ flag, int* __restrict__ ei32)
{
    const int i = blockIdx.x * 256 + threadIdx.x;
    if (i >= 2 * EE) return;
    ei32[i] = flag[0] ? ei_raw[2 * i] : ei_raw[i];
}

// ---------------------------------------------------------------------------
// GEMM: dst = x @ W^T (f32). 64 rows x 64 cols per block, 256 threads.
// blockIdx.y: bit0 = column half, bit1 = (Wl->xl) / (Wr->xr).
// LDS: wt[c][j] transposed 32KB; xs[32][132] pad+4 keeps float4 stores 16B
// aligned (row stride 528B) AND spreads the 4 per-wave row-reads across
// banks (132 mod 32 = 4 -> banks rg*4+c, distinct for rg=0..3).
// ---------------------------------------------------------------------------
__global__ __launch_bounds__(256) void gemm_kernel(
    const float* __restrict__ x, const float* __restrict__ Wl,
    const float* __restrict__ Wr, float* __restrict__ xl, float* __restrict__ xr)
{
    __shared__ float wt[CIN][64];       // 32 KB, [c][j]
    __shared__ float xs[32][CIN + 4];   // 16.5 KB
    const int t = threadIdx.x;
    const int jh = blockIdx.y & 1;
    const float* __restrict__ W = (blockIdx.y & 2) ? Wr : Wl;
    float* __restrict__ dst = (blockIdx.y & 2) ? xr : xl;

    // stage W transposed; lanes iterate j (consecutive) -> conflict-free LDS stores
    for (int i = t; i < 64 * 32; i += 256) {
        const int j = i & 63, c4 = i >> 6;
        const float4 v = *(const float4*)(W + (size_t)(jh * 64 + j) * CIN + c4 * 4);
        wt[c4 * 4 + 0][j] = v.x; wt[c4 * 4 + 1][j] = v.y;
        wt[c4 * 4 + 2][j] = v.z; wt[c4 * 4 + 3][j] = v.w;
    }

    const int row0 = blockIdx.x * 64;
    const int jq = (t & 15) * 4;
    const int rg = t >> 4;
    float acc[4][4] = {};

    for (int ph = 0; ph < 2; ++ph) {
        __syncthreads();
        // stage 32 rows of x
        for (int i = t; i < 32 * 32; i += 256) {
            const int r = i >> 5, c4 = i & 31;
            float4 v = {0.f, 0.f, 0.f, 0.f};
            const int gr = row0 + ph * 32 + r;
            if (gr < NN) v = *(const float4*)(x + (size_t)gr * CIN + c4 * 4);
            *(float4*)(&xs[r][c4 * 4]) = v;
        }
        __syncthreads();
        #pragma unroll 8
        for (int c = 0; c < CIN; ++c) {
            const float4 wf = *(const float4*)(&wt[c][jq]);
            #pragma unroll
            for (int k = 0; k < 2; ++k) {
                const float xf = xs[rg + 16 * k][c];
                const int ka = ph * 2 + k;
                acc[ka][0] = fmaf(xf, wf.x, acc[ka][0]);
                acc[ka][1] = fmaf(xf, wf.y, acc[ka][1]);
                acc[ka][2] = fmaf(xf, wf.z, acc[ka][2]);
                acc[ka][3] = fmaf(xf, wf.w, acc[ka][3]);
            }
        }
    }

    #pragma unroll
    for (int ka = 0; ka < 4; ++ka) {
        const int r = row0 + (ka >> 1) * 32 + rg + 16 * (ka & 1);
        if (r < NN) {
            float4 o = {acc[ka][0], acc[ka][1], acc[ka][2], acc[ka][3]};
            *(float4*)(dst + (size_t)r * HD + jh * 64 + jq) = o;
        }
    }
}

// ---------------------------------------------------------------------------
// Per-edge score + atomic max. One wave per edge; lane = h*16 + dd.
// ---------------------------------------------------------------------------
__global__ __launch_bounds__(256) void edge_score_kernel(
    const int* __restrict__ ei32, const float* __restrict__ xl,
    const float* __restrict__ xr, const float* __restrict__ att,
    float* __restrict__ eb, float* __restrict__ emax)
{
    const int lane = threadIdx.x & 63;
    const int wid = blockIdx.x * (blockDim.x >> 6) + (threadIdx.x >> 6);
    const int nw = gridDim.x * (blockDim.x >> 6);
    const int h = lane >> 4, dd = lane & 15;

    const float2 a2 = *(const float2*)(att + h * DD + dd * 2);

    for (int e = wid; e < ETOT; e += nw) {
        int s, d;
        if (e < EE) { s = ei32[e]; d = ei32[EE + e]; } else { s = d = e - EE; }
        const float2 vl = *(const float2*)(xl + (size_t)s * HD + h * DD + dd * 2);
        const float2 vr = *(const float2*)(xr + (size_t)d * HD + h * DD + dd * 2);
        float vx = vl.x + vr.x, vy = vl.y + vr.y;
        vx = vx > 0.f ? vx : NEG * vx;
        vy = vy > 0.f ? vy : NEG * vy;
        float s2 = vx * a2.x + vy * a2.y;
        s2 += __shfl_xor(s2, 1);
        s2 += __shfl_xor(s2, 2);
        s2 += __shfl_xor(s2, 4);
        s2 += __shfl_xor(s2, 8);
        if (dd == 0) {
            eb[(size_t)e * HH + h] = s2;
            if (s2 > 0.f)
                atomicMax((int*)(emax + (size_t)d * HH + h), __float_as_int(s2));
        }
    }
}

// ---------------------------------------------------------------------------
// exp(e - emax[dst]) and denom accumulation
// ---------------------------------------------------------------------------
__global__ __launch_bounds__(256) void exp_kernel(
    const int* __restrict__ ei32, float* __restrict__ eb,
    const float* __restrict__ emax, float* __restrict__ denom)
{
    const int t = blockIdx.x * blockDim.x + threadIdx.x;
    if (t >= ETOT * HH) return;
    const int e = t >> 2, h = t & 3;
    const int d = (e < EE) ? ei32[EE + e] : (e - EE);
    const float v = __expf(eb[t] - emax[(size_t)d * HH + h]);
    eb[t] = v;
    atomicAdd(denom + (size_t)d * HH + h, v);
}

__global__ __launch_bounds__(256) void rcp_kernel(float* __restrict__ denom)
{
    const int t = blockIdx.x * blockDim.x + threadIdx.x;
    if (t >= NN * HH) return;
    denom[t] = 1.0f / fmaxf(denom[t], 1e-16f);
}

// ---------------------------------------------------------------------------
// acc[dst][d] += sum_h alpha_h * xr[src][h][d]; head-reduce via shfl first.
// ---------------------------------------------------------------------------
__global__ __launch_bounds__(256) void aggregate_kernel(
    const int* __restrict__ ei32, const float* __restrict__ xr,
    const float* __restrict__ eb, const float* __restrict__ denom,
    float* __restrict__ acc)
{
    const int lane = threadIdx.x & 63;
    const int wid = blockIdx.x * (blockDim.x >> 6) + (threadIdx.x >> 6);
    const int nw = gridDim.x * (blockDim.x >> 6);
    const int h = lane >> 4, dd = lane & 15;

    for (int e = wid; e < ETOT; e += nw) {
        int s, d;
        if (e < EE) { s = ei32[e]; d = ei32[EE + e]; } else { s = d = e - EE; }
        const float alpha = eb[(size_t)e * HH + h] * denom[(size_t)d * HH + h];
        const float2 vr = *(const float2*)(xr + (size_t)s * HD + h * DD + dd * 2);
        float vx = vr.x * alpha, vy = vr.y * alpha;
        vx += __shfl_xor(vx, 16); vy += __shfl_xor(vy, 16);
        vx += __shfl_xor(vx, 32); vy += __shfl_xor(vy, 32);
        if (h == 0) {
            atomicAdd(acc + (size_t)d * DD + dd * 2, vx);
            atomicAdd(acc + (size_t)d * DD + dd * 2 + 1, vy);
        }
    }
}

// ---------------------------------------------------------------------------
// out[n][d] = acc[n][d] * 0.25 + bias[d]   (f32 output — reference is f32)
// ---------------------------------------------------------------------------
__global__ __launch_bounds__(256) void final_kernel(
    const float* __restrict__ acc, const float* __restrict__ bias,
    float* __restrict__ out)
{
    const int t = blockIdx.x * blockDim.x + threadIdx.x;
    const int d = t & (DD - 1);
    out[t] = acc[t] * 0.25f + bias[d];
}

extern "C" void kernel_launch(void* const* d_in, const int* in_sizes, int n_in,
                              void* d_out, int out_size, void* d_ws, size_t ws_size,
                              hipStream_t stream)
{
    const float* x    = (const float*)d_in[0];
    const int*   ei   = (const int*)d_in[1];
    const float* Wl   = (const float*)d_in[2];
    const float* Wr   = (const float*)d_in[3];
    const float* att  = (const float*)d_in[4];
    const float* bias = (const float*)d_in[5];
    float* out = (float*)d_out;

    float* ws    = (float*)d_ws;
    int*   flag  = (int*)ws;
    int*   ei32  = (int*)(ws + EI_OFF);
    float* xl    = ws + XL_OFF;
    float* xr    = ws + XR_OFF;
    float* eb    = ws + EB_OFF;
    float* emax  = ws + EMAX_OFF;
    float* denom = ws + DEN_OFF;
    float* acc   = ws + ACC_OFF;

    // zero emax, denom, acc (contiguous 8 MB)
    hipMemsetAsync(emax, 0, (size_t)(2 * NN * HH + NN * DD) * sizeof(float), stream);

    hipLaunchKernelGGL(detect_kernel, dim3(1), dim3(64), 0, stream, ei, flag);
    hipLaunchKernelGGL(convert_ei_kernel, dim3((2 * EE + 255) / 256), dim3(256), 0, stream,
                       ei, flag, ei32);
    hipLaunchKernelGGL(gemm_kernel, dim3((NN + 63) / 64, 4), dim3(256), 0, stream,
                       x, Wl, Wr, xl, xr);
    hipLaunchKernelGGL(edge_score_kernel, dim3(2048), dim3(256), 0, stream,
                       ei32, xl, xr, att, eb, emax);
    hipLaunchKernelGGL(exp_kernel, dim3((ETOT * HH + 255) / 256), dim3(256), 0, stream,
                       ei32, eb, emax, denom);
    hipLaunchKernelGGL(rcp_kernel, dim3((NN * HH + 255) / 256), dim3(256), 0, stream,
                       denom);
    hipLaunchKernelGGL(aggregate_kernel, dim3(2048), dim3(256), 0, stream,
                       ei32, xr, eb, denom, acc);
    hipLaunchKernelGGL(final_kernel, dim3(NN * DD / 256), dim3(256), 0, stream,
                       acc, bias, out);
}

// Round 7
// 367.975 us; speedup vs baseline: 1.2780x; 1.2780x over previous
//
#include <hip/hip_runtime.h>
#include <hip/hip_bf16.h>

#define NN 50000
#define CIN 128
#define HH 4
#define DD 32
#define HD 128
#define EE 800000
#define ETOT (EE + NN)
#define NEG 0.2f

typedef unsigned short ushortT;
typedef unsigned int uintT;
typedef ushortT ushort4v __attribute__((ext_vector_type(4)));

// ---------------------------------------------------------------------------
// ws layout (units of 4B floats):
//   [0]        : flag
//   EI_OFF   = 16         : ei32 (2*EE ints = 1.6M)
//   XLH_OFF  = 1600016    : xl bf16 (NN*128 ushorts = 3.2M float-slots)
//   XRH_OFF  = 4800016    : xr bf16 (3.2M float-slots)
//   EB_OFF   = 8000016    : per-edge exp(score) (ETOT*4 f32 = 3.4M)
//   DEN_OFF  = 11400016   : per-(node,head) denom (NN*4)
//   ACC_OFF  = 11600016   : output accum (NN*32)
// total 13,200,016 floats = 52.8 MB
// ---------------------------------------------------------------------------
#define EI_OFF   16
#define XLH_OFF  1600016
#define XRH_OFF  4800016
#define EB_OFF   8000016
#define DEN_OFF  11400016
#define ACC_OFF  11600016

__device__ __forceinline__ ushortT f2bf(float f) {
    uintT u = __float_as_uint(f);
    u = (u + 0x7fff + ((u >> 16) & 1)) >> 16;   // RNE
    return (ushortT)u;
}
__device__ __forceinline__ float bflo(uintT u) { return __uint_as_float(u << 16); }
__device__ __forceinline__ float bfhi(uintT u) { return __uint_as_float(u & 0xffff0000u); }

// ---------------------------------------------------------------------------
// Detect int64 vs int32 edge_index: int64 values < 2^31 have zero odd words.
// ---------------------------------------------------------------------------
__global__ void detect_kernel(const int* __restrict__ ei_raw, int* __restrict__ flag)
{
    const int l = threadIdx.x;                // 64 threads
    const int w = ei_raw[2 * l + 1];
    const unsigned long long b = __ballot(w != 0);
    if (l == 0) flag[0] = (b == 0ULL) ? 1 : 0;
}

__global__ __launch_bounds__(256) void convert_ei_kernel(
    const int* __restrict__ ei_raw, const int* __restrict__ flag, int* __restrict__ ei32)
{
    const int i = blockIdx.x * 256 + threadIdx.x;
    if (i >= 2 * EE) return;
    ei32[i] = flag[0] ? ei_raw[2 * i] : ei_raw[i];
}

// ---------------------------------------------------------------------------
// GEMM: dst = bf16(x @ W^T). 64 rows x 64 cols per block, 256 threads.
// blockIdx.y: bit0 = column half, bit1 = (Wl->xl) / (Wr->xr).
// ---------------------------------------------------------------------------
__global__ __launch_bounds__(256) void gemm_kernel(
    const float* __restrict__ x, const float* __restrict__ Wl,
    const float* __restrict__ Wr, ushortT* __restrict__ xlh, ushortT* __restrict__ xrh)
{
    __shared__ float wt[CIN][64];       // 32 KB, [c][j]
    __shared__ float xs[32][CIN + 4];   // 16.5 KB; +4 keeps float4 stores aligned
    const int t = threadIdx.x;
    const int jh = blockIdx.y & 1;
    const float* __restrict__ W = (blockIdx.y & 2) ? Wr : Wl;
    ushortT* __restrict__ dst = (blockIdx.y & 2) ? xrh : xlh;

    for (int i = t; i < 64 * 32; i += 256) {
        const int j = i & 63, c4 = i >> 6;
        const float4 v = *(const float4*)(W + (size_t)(jh * 64 + j) * CIN + c4 * 4);
        wt[c4 * 4 + 0][j] = v.x; wt[c4 * 4 + 1][j] = v.y;
        wt[c4 * 4 + 2][j] = v.z; wt[c4 * 4 + 3][j] = v.w;
    }

    const int row0 = blockIdx.x * 64;
    const int jq = (t & 15) * 4;
    const int rg = t >> 4;
    float acc[4][4] = {};

    for (int ph = 0; ph < 2; ++ph) {
        __syncthreads();
        for (int i = t; i < 32 * 32; i += 256) {
            const int r = i >> 5, c4 = i & 31;
            float4 v = {0.f, 0.f, 0.f, 0.f};
            const int gr = row0 + ph * 32 + r;
            if (gr < NN) v = *(const float4*)(x + (size_t)gr * CIN + c4 * 4);
            *(float4*)(&xs[r][c4 * 4]) = v;
        }
        __syncthreads();
        #pragma unroll 8
        for (int c = 0; c < CIN; ++c) {
            const float4 wf = *(const float4*)(&wt[c][jq]);
            #pragma unroll
            for (int k = 0; k < 2; ++k) {
                const float xf = xs[rg + 16 * k][c];
                const int ka = ph * 2 + k;
                acc[ka][0] = fmaf(xf, wf.x, acc[ka][0]);
                acc[ka][1] = fmaf(xf, wf.y, acc[ka][1]);
                acc[ka][2] = fmaf(xf, wf.z, acc[ka][2]);
                acc[ka][3] = fmaf(xf, wf.w, acc[ka][3]);
            }
        }
    }

    #pragma unroll
    for (int ka = 0; ka < 4; ++ka) {
        const int r = row0 + (ka >> 1) * 32 + rg + 16 * (ka & 1);
        if (r < NN) {
            ushort4v o;
            o.x = f2bf(acc[ka][0]); o.y = f2bf(acc[ka][1]);
            o.z = f2bf(acc[ka][2]); o.w = f2bf(acc[ka][3]);
            *(ushort4v*)(dst + (size_t)r * HD + jh * 64 + jq) = o;
        }
    }
}

// ---------------------------------------------------------------------------
// Fused per-edge score + exp + denom. No max pass: softmax is shift-invariant
// and scores are small (|s| ~ 10 max), so exp() can't overflow f32.
// One wave per edge; lane = h*16 + dd handles d = 2*dd, 2*dd+1.
// ---------------------------------------------------------------------------
__global__ __launch_bounds__(256) void edge_score_kernel(
    const int* __restrict__ ei32, const ushortT* __restrict__ xlh,
    const ushortT* __restrict__ xrh, const float* __restrict__ att,
    float* __restrict__ eb, float* __restrict__ denom)
{
    const int lane = threadIdx.x & 63;
    const int wid = blockIdx.x * (blockDim.x >> 6) + (threadIdx.x >> 6);
    const int nw = gridDim.x * (blockDim.x >> 6);
    const int h = lane >> 4, dd = lane & 15;

    const float2 a2 = *(const float2*)(att + h * DD + dd * 2);

    for (int e = wid; e < ETOT; e += nw) {
        int s, d;
        if (e < EE) { s = ei32[e]; d = ei32[EE + e]; } else { s = d = e - EE; }
        const uintT ul = *(const uintT*)(xlh + (size_t)s * HD + h * DD + dd * 2);
        const uintT ur = *(const uintT*)(xrh + (size_t)d * HD + h * DD + dd * 2);
        float vx = bflo(ul) + bflo(ur);
        float vy = bfhi(ul) + bfhi(ur);
        vx = vx > 0.f ? vx : NEG * vx;
        vy = vy > 0.f ? vy : NEG * vy;
        float s2 = vx * a2.x + vy * a2.y;
        s2 += __shfl_xor(s2, 1);
        s2 += __shfl_xor(s2, 2);
        s2 += __shfl_xor(s2, 4);
        s2 += __shfl_xor(s2, 8);
        if (dd == 0) {
            const float p = __expf(s2);
            eb[(size_t)e * HH + h] = p;
            atomicAdd(denom + (size_t)d * HH + h, p);
        }
    }
}

__global__ __launch_bounds__(256) void rcp_kernel(float* __restrict__ denom)
{
    const int t = blockIdx.x * blockDim.x + threadIdx.x;
    if (t >= NN * HH) return;
    denom[t] = 1.0f / fmaxf(denom[t], 1e-16f);
}

// ---------------------------------------------------------------------------
// acc[dst][d] += sum_h alpha_h * xr[src][h][d]; head-reduce via shfl first.
// ---------------------------------------------------------------------------
__global__ __launch_bounds__(256) void aggregate_kernel(
    const int* __restrict__ ei32, const ushortT* __restrict__ xrh,
    const float* __restrict__ eb, const float* __restrict__ denom,
    float* __restrict__ acc)
{
    const int lane = threadIdx.x & 63;
    const int wid = blockIdx.x * (blockDim.x >> 6) + (threadIdx.x >> 6);
    const int nw = gridDim.x * (blockDim.x >> 6);
    const int h = lane >> 4, dd = lane & 15;

    for (int e = wid; e < ETOT; e += nw) {
        int s, d;
        if (e < EE) { s = ei32[e]; d = ei32[EE + e]; } else { s = d = e - EE; }
        const float alpha = eb[(size_t)e * HH + h] * denom[(size_t)d * HH + h];
        const uintT ur = *(const uintT*)(xrh + (size_t)s * HD + h * DD + dd * 2);
        float vx = bflo(ur) * alpha;
        float vy = bfhi(ur) * alpha;
        vx += __shfl_xor(vx, 16); vy += __shfl_xor(vy, 16);
        vx += __shfl_xor(vx, 32); vy += __shfl_xor(vy, 32);
        if (h == 0) {
            atomicAdd(acc + (size_t)d * DD + dd * 2, vx);
            atomicAdd(acc + (size_t)d * DD + dd * 2 + 1, vy);
        }
    }
}

// ---------------------------------------------------------------------------
// out[n][d] = acc[n][d] * 0.25 + bias[d]   (f32 output)
// ---------------------------------------------------------------------------
__global__ __launch_bounds__(256) void final_kernel(
    const float* __restrict__ acc, const float* __restrict__ bias,
    float* __restrict__ out)
{
    const int t = blockIdx.x * blockDim.x + threadIdx.x;
    const int d = t & (DD - 1);
    out[t] = acc[t] * 0.25f + bias[d];
}

extern "C" void kernel_launch(void* const* d_in, const int* in_sizes, int n_in,
                              void* d_out, int out_size, void* d_ws, size_t ws_size,
                              hipStream_t stream)
{
    const float* x    = (const float*)d_in[0];
    const int*   ei   = (const int*)d_in[1];
    const float* Wl   = (const float*)d_in[2];
    const float* Wr   = (const float*)d_in[3];
    const float* att  = (const float*)d_in[4];
    const float* bias = (const float*)d_in[5];
    float* out = (float*)d_out;

    float*   ws    = (float*)d_ws;
    int*     flag  = (int*)ws;
    int*     ei32  = (int*)(ws + EI_OFF);
    ushortT* xlh   = (ushortT*)(ws + XLH_OFF);
    ushortT* xrh   = (ushortT*)(ws + XRH_OFF);
    float*   eb    = ws + EB_OFF;
    float*   denom = ws + DEN_OFF;
    float*   acc   = ws + ACC_OFF;

    // zero denom + acc (contiguous 7.2 MB)
    hipMemsetAsync(denom, 0, (size_t)(NN * HH + NN * DD) * sizeof(float), stream);

    hipLaunchKernelGGL(detect_kernel, dim3(1), dim3(64), 0, stream, ei, flag);
    hipLaunchKernelGGL(convert_ei_kernel, dim3((2 * EE + 255) / 256), dim3(256), 0, stream,
                       ei, flag, ei32);
    hipLaunchKernelGGL(gemm_kernel, dim3((NN + 63) / 64, 4), dim3(256), 0, stream,
                       x, Wl, Wr, xlh, xrh);
    hipLaunchKernelGGL(edge_score_kernel, dim3(2048), dim3(256), 0, stream,
                       ei32, xlh, xrh, att, eb, denom);
    hipLaunchKernelGGL(rcp_kernel, dim3((NN * HH + 255) / 256), dim3(256), 0, stream,
                       denom);
    hipLaunchKernelGGL(aggregate_kernel, dim3(2048), dim3(256), 0, stream,
                       ei32, xrh, eb, denom, acc);
    hipLaunchKernelGGL(final_kernel, dim3(NN * DD / 256), dim3(256), 0, stream,
                       acc, bias, out);
}

// Round 8
// 306.430 us; speedup vs baseline: 1.5347x; 1.2008x over previous
//
#include <hip/hip_runtime.h>
#include <hip/hip_bf16.h>

#define NN 50000
#define CIN 128
#define HH 4
#define DD 32
#define HD 128
#define EE 800000
#define ETOT (EE + NN)
#define NEG 0.2f

typedef unsigned short ushortT;
typedef unsigned int uintT;
typedef ushortT ushort4v __attribute__((ext_vector_type(4)));

// ---------------------------------------------------------------------------
// ws layout (units of 4B):
//   [0]        : flag (1 = edge_index is int64, 0 = int32)
//   EI_OFF   = 16        : ei32 (2*EE ints)
//   CNT_OFF  = 1600016   : per-node degree count (NN ints)
//   ROW_OFF  = 1650032   : CSR row offsets (NN+1 ints)
//   FILL_OFF = 1700048   : scatter fill counters (NN ints)
//   ESRC_OFF = 1750064   : dst-sorted src indices (ETOT ints)
//   XPH_OFF  = 2600080   : interleaved bf16 rows: xl[n][0..127], xr[n][0..127]
//                          (NN * 256 ushorts = 6.4M float-slots)
// total 9,000,080 floats = 36 MB
// ---------------------------------------------------------------------------
#define EI_OFF   16
#define CNT_OFF  1600016
#define ROW_OFF  1650032
#define FILL_OFF 1700048
#define ESRC_OFF 1750064
#define XPH_OFF  2600080

__device__ __forceinline__ ushortT f2bf(float f) {
    uintT u = __float_as_uint(f);
    u = (u + 0x7fff + ((u >> 16) & 1)) >> 16;   // RNE
    return (ushortT)u;
}
__device__ __forceinline__ float bflo(uintT u) { return __uint_as_float(u << 16); }
__device__ __forceinline__ float bfhi(uintT u) { return __uint_as_float(u & 0xffff0000u); }

// ---------------------------------------------------------------------------
// Detect int64 vs int32 edge_index: int64 values < 2^31 have zero odd words.
// ---------------------------------------------------------------------------
__global__ void detect_kernel(const int* __restrict__ ei_raw, int* __restrict__ flag)
{
    const int l = threadIdx.x;                // 64 threads
    const int w = ei_raw[2 * l + 1];
    const unsigned long long b = __ballot(w != 0);
    if (l == 0) flag[0] = (b == 0ULL) ? 1 : 0;
}

// cnt = 1 (self-loop reserved), fill = 0
__global__ __launch_bounds__(256) void init_kernel(int* __restrict__ cnt, int* __restrict__ fill)
{
    const int i = blockIdx.x * 256 + threadIdx.x;
    if (i < NN) { cnt[i] = 1; fill[i] = 0; }
}

// normalize edge index to int32 and histogram dst
__global__ __launch_bounds__(256) void convert_hist_kernel(
    const int* __restrict__ ei_raw, const int* __restrict__ flag,
    int* __restrict__ ei32, int* __restrict__ cnt)
{
    const int i = blockIdx.x * 256 + threadIdx.x;
    if (i >= 2 * EE) return;
    const int v = flag[0] ? ei_raw[2 * i] : ei_raw[i];
    ei32[i] = v;
    if (i >= EE) atomicAdd(&cnt[v], 1);
}

// ---------------------------------------------------------------------------
// Exclusive prefix sum of cnt[0..NN) -> row[0..NN]. One 1024-thread block;
// shfl-based wave scans + 16-wave combine (few barriers per chunk).
// ---------------------------------------------------------------------------
__global__ __launch_bounds__(1024) void scan_kernel(
    const int* __restrict__ cnt, int* __restrict__ row)
{
    __shared__ int wtot[16];
    __shared__ int chunk_total;
    const int t = threadIdx.x, lane = t & 63, wv = t >> 6;
    int run = 0;
    for (int base = 0; base <= NN; base += 1024) {
        const int i = base + t;
        const int v = (i < NN) ? cnt[i] : 0;
        int acc = v;
        #pragma unroll
        for (int off = 1; off < 64; off <<= 1) {
            const int u = __shfl_up(acc, off, 64);
            if (lane >= off) acc += u;
        }
        if (lane == 63) wtot[wv] = acc;
        __syncthreads();
        if (wv == 0 && lane < 16) {
            const int wvv = wtot[lane];
            int wacc = wvv;
            #pragma unroll
            for (int off = 1; off < 16; off <<= 1) {
                const int u = __shfl_up(wacc, off, 64);
                if (lane >= off) wacc += u;
            }
            wtot[lane] = wacc - wvv;            // exclusive wave offset
            if (lane == 15) chunk_total = wacc;
        }
        __syncthreads();
        if (i <= NN) row[i] = run + wtot[wv] + acc - v;
        run += chunk_total;
        __syncthreads();
    }
}

// place src of each edge (incl. self-loops) into its dst segment
__global__ __launch_bounds__(256) void scatter_kernel(
    const int* __restrict__ ei32, const int* __restrict__ row,
    int* __restrict__ fill, int* __restrict__ esrc)
{
    const int e = blockIdx.x * 256 + threadIdx.x;
    if (e >= ETOT) return;
    int s, d;
    if (e < EE) { s = ei32[e]; d = ei32[EE + e]; } else { s = d = e - EE; }
    const int pos = row[d] + atomicAdd(&fill[d], 1);
    esrc[pos] = s;
}

// ---------------------------------------------------------------------------
// GEMM: xph[r] = [bf16(x@Wl^T) | bf16(x@Wr^T)] interleaved 256-ushort rows.
// 64 rows x 64 cols per block; blockIdx.y: bit0 = col half, bit1 = Wl/Wr.
// ---------------------------------------------------------------------------
__global__ __launch_bounds__(256) void gemm_kernel(
    const float* __restrict__ x, const float* __restrict__ Wl,
    const float* __restrict__ Wr, ushortT* __restrict__ xph)
{
    __shared__ float wt[CIN][64];       // 32 KB, [c][j]
    __shared__ float xs[32][CIN + 4];   // 16.5 KB; +4 keeps float4 stores aligned
    const int t = threadIdx.x;
    const int jh = blockIdx.y & 1;
    const int part = (blockIdx.y & 2) ? 1 : 0;      // 0 = xl, 1 = xr
    const float* __restrict__ W = part ? Wr : Wl;

    for (int i = t; i < 64 * 32; i += 256) {
        const int j = i & 63, c4 = i >> 6;
        const float4 v = *(const float4*)(W + (size_t)(jh * 64 + j) * CIN + c4 * 4);
        wt[c4 * 4 + 0][j] = v.x; wt[c4 * 4 + 1][j] = v.y;
        wt[c4 * 4 + 2][j] = v.z; wt[c4 * 4 + 3][j] = v.w;
    }

    const int row0 = blockIdx.x * 64;
    const int jq = (t & 15) * 4;
    const int rg = t >> 4;
    float acc[4][4] = {};

    for (int ph = 0; ph < 2; ++ph) {
        __syncthreads();
        for (int i = t; i < 32 * 32; i += 256) {
            const int r = i >> 5, c4 = i & 31;
            float4 v = {0.f, 0.f, 0.f, 0.f};
            const int gr = row0 + ph * 32 + r;
            if (gr < NN) v = *(const float4*)(x + (size_t)gr * CIN + c4 * 4);
            *(float4*)(&xs[r][c4 * 4]) = v;
        }
        __syncthreads();
        #pragma unroll 8
        for (int c = 0; c < CIN; ++c) {
            const float4 wf = *(const float4*)(&wt[c][jq]);
            #pragma unroll
            for (int k = 0; k < 2; ++k) {
                const float xf = xs[rg + 16 * k][c];
                const int ka = ph * 2 + k;
                acc[ka][0] = fmaf(xf, wf.x, acc[ka][0]);
                acc[ka][1] = fmaf(xf, wf.y, acc[ka][1]);
                acc[ka][2] = fmaf(xf, wf.z, acc[ka][2]);
                acc[ka][3] = fmaf(xf, wf.w, acc[ka][3]);
            }
        }
    }

    #pragma unroll
    for (int ka = 0; ka < 4; ++ka) {
        const int r = row0 + (ka >> 1) * 32 + rg + 16 * (ka & 1);
        if (r < NN) {
            ushort4v o;
            o.x = f2bf(acc[ka][0]); o.y = f2bf(acc[ka][1]);
            o.z = f2bf(acc[ka][2]); o.w = f2bf(acc[ka][3]);
            *(ushort4v*)(xph + (size_t)r * 256 + part * 128 + jh * 64 + jq) = o;
        }
    }
}

// ---------------------------------------------------------------------------
// Fused per-node GATv2: one wave per node. lane = h*16+dd, covers 2 dims.
// Single pass over the dst-sorted segment: den += exp(s); acc += exp(s)*xr[src].
// (softmax shift-invariance: no max pass needed; scores bounded, f32 safe.)
// No atomics anywhere; one 128B out row write per node.
// ---------------------------------------------------------------------------
__global__ __launch_bounds__(256) void gat_node_kernel(
    const int* __restrict__ row, const int* __restrict__ esrc,
    const ushortT* __restrict__ xph, const float* __restrict__ att,
    const float* __restrict__ bias, float* __restrict__ out)
{
    const int lane = threadIdx.x & 63;
    const int h = lane >> 4, dd = lane & 15;
    const int n = blockIdx.x * 4 + (threadIdx.x >> 6);
    if (n >= NN) return;

    const float2 a2 = *(const float2*)(att + h * DD + dd * 2);
    // this node's xr row (the "+ Wr h_dst" term), resident in regs
    const uintT urn = *(const uintT*)(xph + (size_t)n * 256 + 128 + lane * 2);
    const float rnx = bflo(urn), rny = bfhi(urn);

    const int p0 = row[n], p1 = row[n + 1];
    float den = 0.f, ax = 0.f, ay = 0.f;
    for (int p = p0; p < p1; ++p) {
        const int s = esrc[p];
        const uintT ul = *(const uintT*)(xph + (size_t)s * 256 + lane * 2);
        const uintT us = *(const uintT*)(xph + (size_t)s * 256 + 128 + lane * 2);
        float vx = bflo(ul) + rnx, vy = bfhi(ul) + rny;
        vx = vx > 0.f ? vx : NEG * vx;
        vy = vy > 0.f ? vy : NEG * vy;
        float sc = vx * a2.x + vy * a2.y;
        sc += __shfl_xor(sc, 1);
        sc += __shfl_xor(sc, 2);
        sc += __shfl_xor(sc, 4);
        sc += __shfl_xor(sc, 8);        // per-16-lane-group (per-head) score
        const float pe = __expf(sc);
        den += pe;
        ax = fmaf(pe, bflo(us), ax);
        ay = fmaf(pe, bfhi(us), ay);
    }
    const float inv = 1.f / fmaxf(den, 1e-16f);
    ax *= inv; ay *= inv;
    // mean over heads
    ax += __shfl_xor(ax, 16); ay += __shfl_xor(ay, 16);
    ax += __shfl_xor(ax, 32); ay += __shfl_xor(ay, 32);
    if (h == 0) {
        float2 o;
        o.x = ax * 0.25f + bias[dd * 2];
        o.y = ay * 0.25f + bias[dd * 2 + 1];
        *(float2*)(out + (size_t)n * DD + dd * 2) = o;
    }
}

extern "C" void kernel_launch(void* const* d_in, const int* in_sizes, int n_in,
                              void* d_out, int out_size, void* d_ws, size_t ws_size,
                              hipStream_t stream)
{
    const float* x    = (const float*)d_in[0];
    const int*   ei   = (const int*)d_in[1];
    const float* Wl   = (const float*)d_in[2];
    const float* Wr   = (const float*)d_in[3];
    const float* att  = (const float*)d_in[4];
    const float* bias = (const float*)d_in[5];
    float* out = (float*)d_out;

    float*   ws   = (float*)d_ws;
    int*     flag = (int*)ws;
    int*     ei32 = (int*)(ws + EI_OFF);
    int*     cnt  = (int*)(ws + CNT_OFF);
    int*     row  = (int*)(ws + ROW_OFF);
    int*     fill = (int*)(ws + FILL_OFF);
    int*     esrc = (int*)(ws + ESRC_OFF);
    ushortT* xph  = (ushortT*)(ws + XPH_OFF);

    hipLaunchKernelGGL(detect_kernel, dim3(1), dim3(64), 0, stream, ei, flag);
    hipLaunchKernelGGL(init_kernel, dim3((NN + 255) / 256), dim3(256), 0, stream,
                       cnt, fill);
    hipLaunchKernelGGL(convert_hist_kernel, dim3((2 * EE + 255) / 256), dim3(256), 0, stream,
                       ei, flag, ei32, cnt);
    hipLaunchKernelGGL(scan_kernel, dim3(1), dim3(1024), 0, stream, cnt, row);
    hipLaunchKernelGGL(scatter_kernel, dim3((ETOT + 255) / 256), dim3(256), 0, stream,
                       ei32, row, fill, esrc);
    hipLaunchKernelGGL(gemm_kernel, dim3((NN + 63) / 64, 4), dim3(256), 0, stream,
                       x, Wl, Wr, xph);
    hipLaunchKernelGGL(gat_node_kernel, dim3((NN + 3) / 4), dim3(256), 0, stream,
                       row, esrc, xph, att, bias, out);
}

// Round 9
// 245.214 us; speedup vs baseline: 1.9178x; 1.2496x over previous
//
#include <hip/hip_runtime.h>
#include <hip/hip_bf16.h>

#define NN 50000
#define CIN 128
#define HH 4
#define DD 32
#define HD 128
#define EE 800000
#define ETOT (EE + NN)
#define NEG 0.2f

typedef unsigned short ushortT;
typedef unsigned int uintT;
typedef ushortT ushort4v __attribute__((ext_vector_type(4)));

// ---------------------------------------------------------------------------
// ws layout (units of 4B):
//   [0]        : flag (1 = edge_index is int64, 0 = int32)
//   EI_OFF   = 16        : ei32 (2*EE ints)
//   CNT_OFF  = 1600016   : per-node degree count (NN ints)
//   ROW_OFF  = 1650032   : CSR row offsets (NN+1 ints)
//   FILL_OFF = 1700048   : scatter fill counters (NN ints)
//   ESRC_OFF = 1750064   : dst-sorted src indices (ETOT ints)
//   BTOT_OFF = 2600080   : scan block totals (49 ints)
//   XPH_OFF  = 2600144   : interleaved bf16 rows: xl[n][0..127], xr[n][0..127]
// total ~9,000,144 floats = 36 MB
// ---------------------------------------------------------------------------
#define EI_OFF   16
#define CNT_OFF  1600016
#define ROW_OFF  1650032
#define FILL_OFF 1700048
#define ESRC_OFF 1750064
#define BTOT_OFF 2600080
#define XPH_OFF  2600144
#define SCAN_NB  49          // ceil((NN+1)/1024)

__device__ __forceinline__ ushortT f2bf(float f) {
    uintT u = __float_as_uint(f);
    u = (u + 0x7fff + ((u >> 16) & 1)) >> 16;   // RNE
    return (ushortT)u;
}
__device__ __forceinline__ float bflo(uintT u) { return __uint_as_float(u << 16); }
__device__ __forceinline__ float bfhi(uintT u) { return __uint_as_float(u & 0xffff0000u); }

// ---------------------------------------------------------------------------
// Detect int64 vs int32 edge_index: int64 values < 2^31 have zero odd words.
// ---------------------------------------------------------------------------
__global__ void detect_kernel(const int* __restrict__ ei_raw, int* __restrict__ flag)
{
    const int l = threadIdx.x;                // 64 threads
    const int w = ei_raw[2 * l + 1];
    const unsigned long long b = __ballot(w != 0);
    if (l == 0) flag[0] = (b == 0ULL) ? 1 : 0;
}

// cnt = 1 (self-loop reserved), fill = 0
__global__ __launch_bounds__(256) void init_kernel(int* __restrict__ cnt, int* __restrict__ fill)
{
    const int i = blockIdx.x * 256 + threadIdx.x;
    if (i < NN) { cnt[i] = 1; fill[i] = 0; }
}

// normalize edge index to int32 and histogram dst
__global__ __launch_bounds__(256) void convert_hist_kernel(
    const int* __restrict__ ei_raw, const int* __restrict__ flag,
    int* __restrict__ ei32, int* __restrict__ cnt)
{
    const int i = blockIdx.x * 256 + threadIdx.x;
    if (i >= 2 * EE) return;
    const int v = flag[0] ? ei_raw[2 * i] : ei_raw[i];
    ei32[i] = v;
    if (i >= EE) atomicAdd(&cnt[v], 1);
}

// ---------------------------------------------------------------------------
// Multi-block exclusive scan of cnt[0..NN) -> row[0..NN]
// ---------------------------------------------------------------------------
__global__ __launch_bounds__(1024) void scan1_kernel(
    const int* __restrict__ cnt, int* __restrict__ row, int* __restrict__ btot)
{
    __shared__ int wtot[16];
    const int t = threadIdx.x, lane = t & 63, wv = t >> 6;
    const int i = blockIdx.x * 1024 + t;
    const int v = (i < NN) ? cnt[i] : 0;
    int acc = v;
    #pragma unroll
    for (int off = 1; off < 64; off <<= 1) {
        const int u = __shfl_up(acc, off, 64);
        if (lane >= off) acc += u;
    }
    if (lane == 63) wtot[wv] = acc;
    __syncthreads();
    if (wv == 0 && lane < 16) {
        const int wvv = wtot[lane];
        int wacc = wvv;
        #pragma unroll
        for (int off = 1; off < 16; off <<= 1) {
            const int u = __shfl_up(wacc, off, 64);
            if (lane >= off) wacc += u;
        }
        wtot[lane] = wacc - wvv;            // exclusive wave offset
    }
    __syncthreads();
    const int ex = wtot[wv] + acc - v;      // block-local exclusive prefix
    if (i <= NN) row[i] = ex;
    if (t == 1023) btot[blockIdx.x] = ex + v;
}

__global__ void scan2_kernel(int* __restrict__ btot)   // 1 block, 64 threads
{
    const int lane = threadIdx.x;
    const int v = (lane < SCAN_NB) ? btot[lane] : 0;
    int acc = v;
    #pragma unroll
    for (int off = 1; off < 64; off <<= 1) {
        const int u = __shfl_up(acc, off, 64);
        if (lane >= off) acc += u;
    }
    if (lane < SCAN_NB) btot[lane] = acc - v;          // exclusive
}

__global__ __launch_bounds__(256) void scan3_kernel(
    int* __restrict__ row, const int* __restrict__ btot)
{
    const int i = blockIdx.x * 256 + threadIdx.x;
    if (i <= NN) row[i] += btot[i >> 10];
}

// place src of each edge (incl. self-loops) into its dst segment
__global__ __launch_bounds__(256) void scatter_kernel(
    const int* __restrict__ ei32, const int* __restrict__ row,
    int* __restrict__ fill, int* __restrict__ esrc)
{
    const int e = blockIdx.x * 256 + threadIdx.x;
    if (e >= ETOT) return;
    int s, d;
    if (e < EE) { s = ei32[e]; d = ei32[EE + e]; } else { s = d = e - EE; }
    const int pos = row[d] + atomicAdd(&fill[d], 1);
    esrc[pos] = s;
}

// ---------------------------------------------------------------------------
// GEMM: xph[r] = [bf16(x@Wl^T) | bf16(x@Wr^T)] interleaved 256-ushort rows.
// 64 rows x 64 cols per block; blockIdx.y: bit0 = col half, bit1 = Wl/Wr.
// ---------------------------------------------------------------------------
__global__ __launch_bounds__(256) void gemm_kernel(
    const float* __restrict__ x, const float* __restrict__ Wl,
    const float* __restrict__ Wr, ushortT* __restrict__ xph)
{
    __shared__ float wt[CIN][64];       // 32 KB, [c][j]
    __shared__ float xs[32][CIN + 4];   // 16.5 KB; +4 keeps float4 stores aligned
    const int t = threadIdx.x;
    const int jh = blockIdx.y & 1;
    const int part = (blockIdx.y & 2) ? 1 : 0;      // 0 = xl, 1 = xr
    const float* __restrict__ W = part ? Wr : Wl;

    for (int i = t; i < 64 * 32; i += 256) {
        const int j = i & 63, c4 = i >> 6;
        const float4 v = *(const float4*)(W + (size_t)(jh * 64 + j) * CIN + c4 * 4);
        wt[c4 * 4 + 0][j] = v.x; wt[c4 * 4 + 1][j] = v.y;
        wt[c4 * 4 + 2][j] = v.z; wt[c4 * 4 + 3][j] = v.w;
    }

    const int row0 = blockIdx.x * 64;
    const int jq = (t & 15) * 4;
    const int rg = t >> 4;
    float acc[4][4] = {};

    for (int ph = 0; ph < 2; ++ph) {
        __syncthreads();
        for (int i = t; i < 32 * 32; i += 256) {
            const int r = i >> 5, c4 = i & 31;
            float4 v = {0.f, 0.f, 0.f, 0.f};
            const int gr = row0 + ph * 32 + r;
            if (gr < NN) v = *(const float4*)(x + (size_t)gr * CIN + c4 * 4);
            *(float4*)(&xs[r][c4 * 4]) = v;
        }
        __syncthreads();
        #pragma unroll 8
        for (int c = 0; c < CIN; ++c) {
            const float4 wf = *(const float4*)(&wt[c][jq]);
            #pragma unroll
            for (int k = 0; k < 2; ++k) {
                const float xf = xs[rg + 16 * k][c];
                const int ka = ph * 2 + k;
                acc[ka][0] = fmaf(xf, wf.x, acc[ka][0]);
                acc[ka][1] = fmaf(xf, wf.y, acc[ka][1]);
                acc[ka][2] = fmaf(xf, wf.z, acc[ka][2]);
                acc[ka][3] = fmaf(xf, wf.w, acc[ka][3]);
            }
        }
    }

    #pragma unroll
    for (int ka = 0; ka < 4; ++ka) {
        const int r = row0 + (ka >> 1) * 32 + rg + 16 * (ka & 1);
        if (r < NN) {
            ushort4v o;
            o.x = f2bf(acc[ka][0]); o.y = f2bf(acc[ka][1]);
            o.z = f2bf(acc[ka][2]); o.w = f2bf(acc[ka][3]);
            *(ushort4v*)(xph + (size_t)r * 256 + part * 128 + jh * 64 + jq) = o;
        }
    }
}

// ---------------------------------------------------------------------------
// Fused per-node GATv2: one wave per node, lane = h*16+dd covers 2 dims.
// Unrolled 2 edges/iter: 4 independent gathers in flight (MLP x2),
// interleaved shfl reduce chains. No atomics; one out-row write per node.
// ---------------------------------------------------------------------------
__global__ __launch_bounds__(256) void gat_node_kernel(
    const int* __restrict__ row, const int* __restrict__ esrc,
    const ushortT* __restrict__ xph, const float* __restrict__ att,
    const float* __restrict__ bias, float* __restrict__ out)
{
    const int lane = threadIdx.x & 63;
    const int h = lane >> 4, dd = lane & 15;
    const int n = blockIdx.x * 4 + (threadIdx.x >> 6);
    if (n >= NN) return;

    const float2 a2 = *(const float2*)(att + h * DD + dd * 2);
    const uintT urn = *(const uintT*)(xph + (size_t)n * 256 + 128 + lane * 2);
    const float rnx = bflo(urn), rny = bfhi(urn);

    const int p0 = row[n], p1 = row[n + 1];
    float den = 0.f, ax = 0.f, ay = 0.f;
    int p = p0;

    for (; p + 2 <= p1; p += 2) {
        const int sa = esrc[p];
        const int sb = esrc[p + 1];
        const uintT ula = *(const uintT*)(xph + (size_t)sa * 256 + lane * 2);
        const uintT usa = *(const uintT*)(xph + (size_t)sa * 256 + 128 + lane * 2);
        const uintT ulb = *(const uintT*)(xph + (size_t)sb * 256 + lane * 2);
        const uintT usb = *(const uintT*)(xph + (size_t)sb * 256 + 128 + lane * 2);

        float vxa = bflo(ula) + rnx, vya = bfhi(ula) + rny;
        float vxb = bflo(ulb) + rnx, vyb = bfhi(ulb) + rny;
        vxa = vxa > 0.f ? vxa : NEG * vxa;
        vya = vya > 0.f ? vya : NEG * vya;
        vxb = vxb > 0.f ? vxb : NEG * vxb;
        vyb = vyb > 0.f ? vyb : NEG * vyb;
        float sca = vxa * a2.x + vya * a2.y;
        float scb = vxb * a2.x + vyb * a2.y;
        sca += __shfl_xor(sca, 1);  scb += __shfl_xor(scb, 1);
        sca += __shfl_xor(sca, 2);  scb += __shfl_xor(scb, 2);
        sca += __shfl_xor(sca, 4);  scb += __shfl_xor(scb, 4);
        sca += __shfl_xor(sca, 8);  scb += __shfl_xor(scb, 8);
        const float pa = __expf(sca);
        const float pb = __expf(scb);
        den += pa + pb;
        ax = fmaf(pa, bflo(usa), ax); ax = fmaf(pb, bflo(usb), ax);
        ay = fmaf(pa, bfhi(usa), ay); ay = fmaf(pb, bfhi(usb), ay);
    }
    if (p < p1) {
        const int s = esrc[p];
        const uintT ul = *(const uintT*)(xph + (size_t)s * 256 + lane * 2);
        const uintT us = *(const uintT*)(xph + (size_t)s * 256 + 128 + lane * 2);
        float vx = bflo(ul) + rnx, vy = bfhi(ul) + rny;
        vx = vx > 0.f ? vx : NEG * vx;
        vy = vy > 0.f ? vy : NEG * vy;
        float sc = vx * a2.x + vy * a2.y;
        sc += __shfl_xor(sc, 1);
        sc += __shfl_xor(sc, 2);
        sc += __shfl_xor(sc, 4);
        sc += __shfl_xor(sc, 8);
        const float pe = __expf(sc);
        den += pe;
        ax = fmaf(pe, bflo(us), ax);
        ay = fmaf(pe, bfhi(us), ay);
    }

    const float inv = 1.f / fmaxf(den, 1e-16f);
    ax *= inv; ay *= inv;
    ax += __shfl_xor(ax, 16); ay += __shfl_xor(ay, 16);
    ax += __shfl_xor(ax, 32); ay += __shfl_xor(ay, 32);
    if (h == 0) {
        float2 o;
        o.x = ax * 0.25f + bias[dd * 2];
        o.y = ay * 0.25f + bias[dd * 2 + 1];
        *(float2*)(out + (size_t)n * DD + dd * 2) = o;
    }
}

extern "C" void kernel_launch(void* const* d_in, const int* in_sizes, int n_in,
                              void* d_out, int out_size, void* d_ws, size_t ws_size,
                              hipStream_t stream)
{
    const float* x    = (const float*)d_in[0];
    const int*   ei   = (const int*)d_in[1];
    const float* Wl   = (const float*)d_in[2];
    const float* Wr   = (const float*)d_in[3];
    const float* att  = (const float*)d_in[4];
    const float* bias = (const float*)d_in[5];
    float* out = (float*)d_out;

    float*   ws   = (float*)d_ws;
    int*     flag = (int*)ws;
    int*     ei32 = (int*)(ws + EI_OFF);
    int*     cnt  = (int*)(ws + CNT_OFF);
    int*     row  = (int*)(ws + ROW_OFF);
    int*     fill = (int*)(ws + FILL_OFF);
    int*     esrc = (int*)(ws + ESRC_OFF);
    int*     btot = (int*)(ws + BTOT_OFF);
    ushortT* xph  = (ushortT*)(ws + XPH_OFF);

    hipLaunchKernelGGL(detect_kernel, dim3(1), dim3(64), 0, stream, ei, flag);
    hipLaunchKernelGGL(init_kernel, dim3((NN + 255) / 256), dim3(256), 0, stream,
                       cnt, fill);
    hipLaunchKernelGGL(convert_hist_kernel, dim3((2 * EE + 255) / 256), dim3(256), 0, stream,
                       ei, flag, ei32, cnt);
    hipLaunchKernelGGL(scan1_kernel, dim3(SCAN_NB), dim3(1024), 0, stream, cnt, row, btot);
    hipLaunchKernelGGL(scan2_kernel, dim3(1), dim3(64), 0, stream, btot);
    hipLaunchKernelGGL(scan3_kernel, dim3((NN + 256) / 256), dim3(256), 0, stream, row, btot);
    hipLaunchKernelGGL(scatter_kernel, dim3((ETOT + 255) / 256), dim3(256), 0, stream,
                       ei32, row, fill, esrc);
    hipLaunchKernelGGL(gemm_kernel, dim3((NN + 63) / 64, 4), dim3(256), 0, stream,
                       x, Wl, Wr, xph);
    hipLaunchKernelGGL(gat_node_kernel, dim3((NN + 3) / 4), dim3(256), 0, stream,
                       row, esrc, xph, att, bias, out);
}

// Round 10
// 215.027 us; speedup vs baseline: 2.1870x; 1.1404x over previous
//
#include <hip/hip_runtime.h>
#include <hip/hip_bf16.h>

#define NN 50000
#define CIN 128
#define HH 4
#define DD 32
#define HD 128
#define EE 800000
#define ETOT (EE + NN)
#define NEG 0.2f

typedef unsigned short ushortT;
typedef unsigned int uintT;
typedef ushortT ushort4v __attribute__((ext_vector_type(4)));
typedef __attribute__((ext_vector_type(8))) short bf16x8;
typedef __attribute__((ext_vector_type(4))) float f32x4;

// ---------------------------------------------------------------------------
// ws layout (units of 4B):
//   [0]       : flag (1 = edge_index is int64, 0 = int32)
//   CNT_OFF  = 16       : per-node degree count (NN ints)
//   ROW_OFF  = 50016    : CSR row offsets (NN+1 ints)
//   FILL_OFF = 100032   : scatter fill counters (NN ints)
//   ESRC_OFF = 150048   : dst-sorted src indices (ETOT ints)
//   BTOT_OFF = 1000048  : scan block totals (64 ints)
//   WBF_OFF  = 1000112  : W bf16 [256][128] (16384 float-slots)
//   XBF_OFF  = 1016496  : x bf16 [NN][128]  (3.2M float-slots)
//   XPH_OFF  = 4216496  : interleaved bf16 rows xl|xr [NN][256] (6.4M slots)
// total 10,616,496 floats = 42.5 MB
// ---------------------------------------------------------------------------
#define CNT_OFF  16
#define ROW_OFF  50016
#define FILL_OFF 100032
#define ESRC_OFF 150048
#define BTOT_OFF 1000048
#define WBF_OFF  1000112
#define XBF_OFF  1016496
#define XPH_OFF  4216496
#define SCAN_NB  49          // ceil((NN+1)/1024)
#define NX8      (NN * CIN / 8)   // 800000 8-element chunks of x

__device__ __forceinline__ ushortT f2bf(float f) {
    uintT u = __float_as_uint(f);
    u = (u + 0x7fff + ((u >> 16) & 1)) >> 16;   // RNE
    return (ushortT)u;
}
__device__ __forceinline__ float bflo(uintT u) { return __uint_as_float(u << 16); }
__device__ __forceinline__ float bfhi(uintT u) { return __uint_as_float(u & 0xffff0000u); }

// ---------------------------------------------------------------------------
// Detect int64 vs int32 edge_index: int64 values < 2^31 have zero odd words.
// ---------------------------------------------------------------------------
__global__ void detect_kernel(const int* __restrict__ ei_raw, int* __restrict__ flag)
{
    const int l = threadIdx.x;                // 64 threads
    const int w = ei_raw[2 * l + 1];
    const unsigned long long b = __ballot(w != 0);
    if (l == 0) flag[0] = (b == 0ULL) ? 1 : 0;
}

// cnt = 1 (self-loop reserved), fill = 0
__global__ __launch_bounds__(256) void init_kernel(int* __restrict__ cnt, int* __restrict__ fill)
{
    const int i = blockIdx.x * 256 + threadIdx.x;
    if (i < NN) { cnt[i] = 1; fill[i] = 0; }
}

// histogram dst straight from the raw (possibly int64) edge index
__global__ __launch_bounds__(256) void hist_kernel(
    const int* __restrict__ ei_raw, const int* __restrict__ flag, int* __restrict__ cnt)
{
    const int e = blockIdx.x * 256 + threadIdx.x;
    if (e >= EE) return;
    const int d = flag[0] ? ei_raw[2 * (EE + e)] : ei_raw[EE + e];
    atomicAdd(&cnt[d], 1);
}

// ---------------------------------------------------------------------------
// Multi-block exclusive scan of cnt[0..NN) -> row[0..NN]
// ---------------------------------------------------------------------------
__global__ __launch_bounds__(1024) void scan1_kernel(
    const int* __restrict__ cnt, int* __restrict__ row, int* __restrict__ btot)
{
    __shared__ int wtot[16];
    const int t = threadIdx.x, lane = t & 63, wv = t >> 6;
    const int i = blockIdx.x * 1024 + t;
    const int v = (i < NN) ? cnt[i] : 0;
    int acc = v;
    #pragma unroll
    for (int off = 1; off < 64; off <<= 1) {
        const int u = __shfl_up(acc, off, 64);
        if (lane >= off) acc += u;
    }
    if (lane == 63) wtot[wv] = acc;
    __syncthreads();
    if (wv == 0 && lane < 16) {
        const int wvv = wtot[lane];
        int wacc = wvv;
        #pragma unroll
        for (int off = 1; off < 16; off <<= 1) {
            const int u = __shfl_up(wacc, off, 64);
            if (lane >= off) wacc += u;
        }
        wtot[lane] = wacc - wvv;            // exclusive wave offset
    }
    __syncthreads();
    const int ex = wtot[wv] + acc - v;      // block-local exclusive prefix
    if (i <= NN) row[i] = ex;
    if (t == 1023) btot[blockIdx.x] = ex + v;
}

__global__ void scan2_kernel(int* __restrict__ btot)   // 1 block, 64 threads
{
    const int lane = threadIdx.x;
    const int v = (lane < SCAN_NB) ? btot[lane] : 0;
    int acc = v;
    #pragma unroll
    for (int off = 1; off < 64; off <<= 1) {
        const int u = __shfl_up(acc, off, 64);
        if (lane >= off) acc += u;
    }
    if (lane < SCAN_NB) btot[lane] = acc - v;          // exclusive
}

__global__ __launch_bounds__(256) void scan3_kernel(
    int* __restrict__ row, const int* __restrict__ btot)
{
    const int i = blockIdx.x * 256 + threadIdx.x;
    if (i <= NN) row[i] += btot[i >> 10];
}

// place src of each edge (incl. self-loops) into its dst segment
__global__ __launch_bounds__(256) void scatter_kernel(
    const int* __restrict__ ei_raw, const int* __restrict__ flag,
    const int* __restrict__ row, int* __restrict__ fill, int* __restrict__ esrc)
{
    const int e = blockIdx.x * 256 + threadIdx.x;
    if (e >= ETOT) return;
    int s, d;
    if (e < EE) {
        if (flag[0]) { s = ei_raw[2 * e]; d = ei_raw[2 * (EE + e)]; }
        else         { s = ei_raw[e];     d = ei_raw[EE + e]; }
    } else { s = d = e - EE; }
    const int pos = row[d] + atomicAdd(&fill[d], 1);
    esrc[pos] = s;
}

// ---------------------------------------------------------------------------
// Convert x and Wl|Wr to bf16 (one pass, 8 elems/thread)
// ---------------------------------------------------------------------------
__global__ __launch_bounds__(256) void prep_kernel(
    const float* __restrict__ x, const float* __restrict__ Wl,
    const float* __restrict__ Wr, ushortT* __restrict__ xbf, ushortT* __restrict__ wbf)
{
    const int i = blockIdx.x * 256 + threadIdx.x;
    const float* src; ushortT* dst; int off;
    if (i < NX8)             { src = x;  dst = xbf;              off = i; }
    else if (i < NX8 + 2048) { src = Wl; dst = wbf;              off = i - NX8; }
    else if (i < NX8 + 4096) { src = Wr; dst = wbf + 128 * 128;  off = i - NX8 - 2048; }
    else return;
    const float4 v0 = *(const float4*)(src + (size_t)off * 8);
    const float4 v1 = *(const float4*)(src + (size_t)off * 8 + 4);
    bf16x8 o;
    o[0] = f2bf(v0.x); o[1] = f2bf(v0.y); o[2] = f2bf(v0.z); o[3] = f2bf(v0.w);
    o[4] = f2bf(v1.x); o[5] = f2bf(v1.y); o[6] = f2bf(v1.z); o[7] = f2bf(v1.w);
    *(bf16x8*)(dst + (size_t)off * 8) = o;
}

// ---------------------------------------------------------------------------
// MFMA GEMM: xph[n] = [bf16(x@Wl^T) | bf16(x@Wr^T)], 256-ushort rows.
// Block = 256 thr = 4 waves, computes 32 rows x 64 cols of one (part,colhalf).
// Wave w: row-group rg=w&1 (16 rows), cols (w>>1)*32 .. +31 (2 MFMA tiles).
// A-frag: row=lane&15, k=(lane>>4)*8+j (16B contig); B-frag: col=lane&15, same k.
// C/D: col=lane&15, row=(lane>>4)*4+reg (m89-verified). Epilogue via LDS for
// coalesced 16B stores.
// ---------------------------------------------------------------------------
__global__ __launch_bounds__(256) void gemm_mfma_kernel(
    const ushortT* __restrict__ xbf, const ushortT* __restrict__ wbf,
    ushortT* __restrict__ xph)
{
    __shared__ ushortT tl[32][72];      // +8 pad: conflict-light b16 writes, 16B-aligned rows (144B)
    const int w = threadIdx.x >> 6, l = threadIdx.x & 63;
    const int row0 = blockIdx.x * 32;
    const int part = blockIdx.y >> 1, colhalf = blockIdx.y & 1;
    const int rg = w & 1;
    const int cbase = (w >> 1) * 32;    // local col base (within the 64-col half)

    const int arow = row0 + rg * 16 + (l & 15);
    const int arow_c = arow < NN ? arow : NN - 1;     // clamp tail reads
    const int kbase = (l >> 4) * 8;
    const ushortT* xrow  = xbf + (size_t)arow_c * 128 + kbase;
    const ushortT* wrow0 = wbf + (size_t)(part * 128 + colhalf * 64 + cbase + (l & 15)) * 128 + kbase;
    const ushortT* wrow1 = wrow0 + 16 * 128;

    f32x4 acc0 = {}, acc1 = {};
    #pragma unroll
    for (int ks = 0; ks < 4; ++ks) {
        const bf16x8 a  = *(const bf16x8*)(xrow  + ks * 32);
        const bf16x8 b0 = *(const bf16x8*)(wrow0 + ks * 32);
        const bf16x8 b1 = *(const bf16x8*)(wrow1 + ks * 32);
        acc0 = __builtin_amdgcn_mfma_f32_16x16x32_bf16(a, b0, acc0, 0, 0, 0);
        acc1 = __builtin_amdgcn_mfma_f32_16x16x32_bf16(a, b1, acc1, 0, 0, 0);
    }

    #pragma unroll
    for (int j = 0; j < 4; ++j) {
        const int r = rg * 16 + (l >> 4) * 4 + j;
        tl[r][cbase + (l & 15)]      = f2bf(acc0[j]);
        tl[r][cbase + 16 + (l & 15)] = f2bf(acc1[j]);
    }
    __syncthreads();

    const int lrow = threadIdx.x >> 3, seg = threadIdx.x & 7;
    const int gr = row0 + lrow;
    if (gr < NN) {
        *(bf16x8*)(xph + (size_t)gr * 256 + part * 128 + colhalf * 64 + seg * 8) =
            *(const bf16x8*)(&tl[lrow][seg * 8]);
    }
}

// ---------------------------------------------------------------------------
// Fused per-node GATv2: one wave per node, lane = h*16+dd covers 2 dims.
// Unrolled 2 edges/iter. No atomics; one out-row write per node.
// ---------------------------------------------------------------------------
__global__ __launch_bounds__(256) void gat_node_kernel(
    const int* __restrict__ row, const int* __restrict__ esrc,
    const ushortT* __restrict__ xph, const float* __restrict__ att,
    const float* __restrict__ bias, float* __restrict__ out)
{
    const int lane = threadIdx.x & 63;
    const int h = lane >> 4, dd = lane & 15;
    const int n = blockIdx.x * 4 + (threadIdx.x >> 6);
    if (n >= NN) return;

    const float2 a2 = *(const float2*)(att + h * DD + dd * 2);
    const uintT urn = *(const uintT*)(xph + (size_t)n * 256 + 128 + lane * 2);
    const float rnx = bflo(urn), rny = bfhi(urn);

    const int p0 = row[n], p1 = row[n + 1];
    float den = 0.f, ax = 0.f, ay = 0.f;
    int p = p0;

    for (; p + 2 <= p1; p += 2) {
        const int sa = esrc[p];
        const int sb = esrc[p + 1];
        const uintT ula = *(const uintT*)(xph + (size_t)sa * 256 + lane * 2);
        const uintT usa = *(const uintT*)(xph + (size_t)sa * 256 + 128 + lane * 2);
        const uintT ulb = *(const uintT*)(xph + (size_t)sb * 256 + lane * 2);
        const uintT usb = *(const uintT*)(xph + (size_t)sb * 256 + 128 + lane * 2);

        float vxa = bflo(ula) + rnx, vya = bfhi(ula) + rny;
        float vxb = bflo(ulb) + rnx, vyb = bfhi(ulb) + rny;
        vxa = vxa > 0.f ? vxa : NEG * vxa;
        vya = vya > 0.f ? vya : NEG * vya;
        vxb = vxb > 0.f ? vxb : NEG * vxb;
        vyb = vyb > 0.f ? vyb : NEG * vyb;
        float sca = vxa * a2.x + vya * a2.y;
        float scb = vxb * a2.x + vyb * a2.y;
        sca += __shfl_xor(sca, 1);  scb += __shfl_xor(scb, 1);
        sca += __shfl_xor(sca, 2);  scb += __shfl_xor(scb, 2);
        sca += __shfl_xor(sca, 4);  scb += __shfl_xor(scb, 4);
        sca += __shfl_xor(sca, 8);  scb += __shfl_xor(scb, 8);
        const float pa = __expf(sca);
        const float pb = __expf(scb);
        den += pa + pb;
        ax = fmaf(pa, bflo(usa), ax); ax = fmaf(pb, bflo(usb), ax);
        ay = fmaf(pa, bfhi(usa), ay); ay = fmaf(pb, bfhi(usb), ay);
    }
    if (p < p1) {
        const int s = esrc[p];
        const uintT ul = *(const uintT*)(xph + (size_t)s * 256 + lane * 2);
        const uintT us = *(const uintT*)(xph + (size_t)s * 256 + 128 + lane * 2);
        float vx = bflo(ul) + rnx, vy = bfhi(ul) + rny;
        vx = vx > 0.f ? vx : NEG * vx;
        vy = vy > 0.f ? vy : NEG * vy;
        float sc = vx * a2.x + vy * a2.y;
        sc += __shfl_xor(sc, 1);
        sc += __shfl_xor(sc, 2);
        sc += __shfl_xor(sc, 4);
        sc += __shfl_xor(sc, 8);
        const float pe = __expf(sc);
        den += pe;
        ax = fmaf(pe, bflo(us), ax);
        ay = fmaf(pe, bfhi(us), ay);
    }

    const float inv = 1.f / fmaxf(den, 1e-16f);
    ax *= inv; ay *= inv;
    ax += __shfl_xor(ax, 16); ay += __shfl_xor(ay, 16);
    ax += __shfl_xor(ax, 32); ay += __shfl_xor(ay, 32);
    if (h == 0) {
        float2 o;
        o.x = ax * 0.25f + bias[dd * 2];
        o.y = ay * 0.25f + bias[dd * 2 + 1];
        *(float2*)(out + (size_t)n * DD + dd * 2) = o;
    }
}

extern "C" void kernel_launch(void* const* d_in, const int* in_sizes, int n_in,
                              void* d_out, int out_size, void* d_ws, size_t ws_size,
                              hipStream_t stream)
{
    const float* x    = (const float*)d_in[0];
    const int*   ei   = (const int*)d_in[1];
    const float* Wl   = (const float*)d_in[2];
    const float* Wr   = (const float*)d_in[3];
    const float* att  = (const float*)d_in[4];
    const float* bias = (const float*)d_in[5];
    float* out = (float*)d_out;

    float*   ws   = (float*)d_ws;
    int*     flag = (int*)ws;
    int*     cnt  = (int*)(ws + CNT_OFF);
    int*     row  = (int*)(ws + ROW_OFF);
    int*     fill = (int*)(ws + FILL_OFF);
    int*     esrc = (int*)(ws + ESRC_OFF);
    int*     btot = (int*)(ws + BTOT_OFF);
    ushortT* wbf  = (ushortT*)(ws + WBF_OFF);
    ushortT* xbf  = (ushortT*)(ws + XBF_OFF);
    ushortT* xph  = (ushortT*)(ws + XPH_OFF);

    hipLaunchKernelGGL(detect_kernel, dim3(1), dim3(64), 0, stream, ei, flag);
    hipLaunchKernelGGL(init_kernel, dim3((NN + 255) / 256), dim3(256), 0, stream,
                       cnt, fill);
    hipLaunchKernelGGL(hist_kernel, dim3((EE + 255) / 256), dim3(256), 0, stream,
                       ei, flag, cnt);
    hipLaunchKernelGGL(prep_kernel, dim3((NX8 + 4096 + 255) / 256), dim3(256), 0, stream,
                       x, Wl, Wr, xbf, wbf);
    hipLaunchKernelGGL(scan1_kernel, dim3(SCAN_NB), dim3(1024), 0, stream, cnt, row, btot);
    hipLaunchKernelGGL(scan2_kernel, dim3(1), dim3(64), 0, stream, btot);
    hipLaunchKernelGGL(scan3_kernel, dim3((NN + 256) / 256), dim3(256), 0, stream, row, btot);
    hipLaunchKernelGGL(scatter_kernel, dim3((ETOT + 255) / 256), dim3(256), 0, stream,
                       ei, flag, row, fill, esrc);
    hipLaunchKernelGGL(gemm_mfma_kernel, dim3((NN + 31) / 32, 4), dim3(256), 0, stream,
                       xbf, wbf, xph);
    hipLaunchKernelGGL(gat_node_kernel, dim3((NN + 3) / 4), dim3(256), 0, stream,
                       row, esrc, xph, att, bias, out);
}

// Round 11
// 190.061 us; speedup vs baseline: 2.4743x; 1.1314x over previous
//
#include <hip/hip_runtime.h>
#include <hip/hip_bf16.h>

#define NN 50000
#define CIN 128
#define HH 4
#define DD 32
#define HD 128
#define EE 800000
#define ETOT (EE + NN)
#define NEG 0.2f

typedef unsigned short ushortT;
typedef unsigned int uintT;
typedef __attribute__((ext_vector_type(8))) short bf16x8;
typedef __attribute__((ext_vector_type(4))) float f32x4;

// ---------------------------------------------------------------------------
// ws layout (units of 4B):
//   [0]       : flag (1 = edge_index is int64, 0 = int32)
//   CNT_OFF  = 16       : per-node extra-degree count (NN ints)   [memset 0]
//   FILL_OFF = 50016    : scatter fill counters (NN ints)         [memset 0]
//   ROW_OFF  = 100032   : CSR row offsets (NN+1 ints)
//   ESRC_OFF = 150048   : dst-sorted src indices (ETOT ints)
//   BTOT_OFF = 1000048  : scan block totals (64 ints)
//   WBF_OFF  = 1000112  : W bf16 [256][128] (16384 float-slots)
//   XPH_OFF  = 1016496  : interleaved bf16 rows xl|xr [NN][256] (3.2M slots)
// total 4,216,496 floats = 16.9 MB
// ---------------------------------------------------------------------------
#define CNT_OFF  16
#define FILL_OFF 50016
#define ROW_OFF  100032
#define ESRC_OFF 150048
#define BTOT_OFF 1000048
#define WBF_OFF  1000112
#define XPH_OFF  1016496
#define SCAN_NB  49          // ceil((NN+1)/1024)

__device__ __forceinline__ ushortT f2bf(float f) {
    uintT u = __float_as_uint(f);
    u = (u + 0x7fff + ((u >> 16) & 1)) >> 16;   // RNE
    return (ushortT)u;
}
__device__ __forceinline__ float bflo(uintT u) { return __uint_as_float(u << 16); }
__device__ __forceinline__ float bfhi(uintT u) { return __uint_as_float(u & 0xffff0000u); }

// ---------------------------------------------------------------------------
// Detect int64 vs int32 edge_index: int64 values < 2^31 have zero odd words.
// ---------------------------------------------------------------------------
__global__ void detect_kernel(const int* __restrict__ ei_raw, int* __restrict__ flag)
{
    const int l = threadIdx.x;                // 64 threads
    const int w = ei_raw[2 * l + 1];
    const unsigned long long b = __ballot(w != 0);
    if (l == 0) flag[0] = (b == 0ULL) ? 1 : 0;
}

// histogram dst straight from the raw (possibly int64) edge index
__global__ __launch_bounds__(256) void hist_kernel(
    const int* __restrict__ ei_raw, const int* __restrict__ flag, int* __restrict__ cnt)
{
    const int e = blockIdx.x * 256 + threadIdx.x;
    if (e >= EE) return;
    const int d = flag[0] ? ei_raw[2 * (EE + e)] : ei_raw[EE + e];
    atomicAdd(&cnt[d], 1);
}

// convert Wl|Wr to bf16: wbf[256][128], rows 0..127 = Wl, 128..255 = Wr
__global__ __launch_bounds__(256) void wprep_kernel(
    const float* __restrict__ Wl, const float* __restrict__ Wr, ushortT* __restrict__ wbf)
{
    const int i = blockIdx.x * 256 + threadIdx.x;   // 4096 threads, 8 elems each
    const float* src = (i < 2048) ? Wl : Wr;
    const int off = (i < 2048) ? i : i - 2048;
    const float4 v0 = *(const float4*)(src + (size_t)off * 8);
    const float4 v1 = *(const float4*)(src + (size_t)off * 8 + 4);
    bf16x8 o;
    o[0] = f2bf(v0.x); o[1] = f2bf(v0.y); o[2] = f2bf(v0.z); o[3] = f2bf(v0.w);
    o[4] = f2bf(v1.x); o[5] = f2bf(v1.y); o[6] = f2bf(v1.z); o[7] = f2bf(v1.w);
    *(bf16x8*)(wbf + ((i < 2048) ? 0 : 16384) + (size_t)off * 8) = o;
}

// ---------------------------------------------------------------------------
// scan1: block-local exclusive scan of (cnt[i]+1)  [+1 = self-loop]
// ---------------------------------------------------------------------------
__global__ __launch_bounds__(1024) void scan1_kernel(
    const int* __restrict__ cnt, int* __restrict__ row, int* __restrict__ btot)
{
    __shared__ int wtot[16];
    const int t = threadIdx.x, lane = t & 63, wv = t >> 6;
    const int i = blockIdx.x * 1024 + t;
    const int v = (i < NN) ? cnt[i] + 1 : 0;
    int acc = v;
    #pragma unroll
    for (int off = 1; off < 64; off <<= 1) {
        const int u = __shfl_up(acc, off, 64);
        if (lane >= off) acc += u;
    }
    if (lane == 63) wtot[wv] = acc;
    __syncthreads();
    if (wv == 0 && lane < 16) {
        const int wvv = wtot[lane];
        int wacc = wvv;
        #pragma unroll
        for (int off = 1; off < 16; off <<= 1) {
            const int u = __shfl_up(wacc, off, 64);
            if (lane >= off) wacc += u;
        }
        wtot[lane] = wacc - wvv;            // exclusive wave offset
    }
    __syncthreads();
    const int ex = wtot[wv] + acc - v;      // block-local exclusive prefix
    if (i <= NN) row[i] = ex;
    if (t == 1023) btot[blockIdx.x] = ex + v;
}

// scan3: each block wave-reduces its own btot prefix, adds to row
__global__ __launch_bounds__(256) void scan3_kernel(
    int* __restrict__ row, const int* __restrict__ btot)
{
    const int i = blockIdx.x * 256 + threadIdx.x;
    const int chunk = blockIdx.x >> 2;              // 1024-chunk id (const per block)
    const int lane = threadIdx.x & 63;
    int v = (lane < chunk) ? btot[lane] : 0;
    #pragma unroll
    for (int off = 1; off < 64; off <<= 1) v += __shfl_xor(v, off);
    if (i <= NN) row[i] += v;
}

// place src of each edge (incl. self-loops) into its dst segment
__global__ __launch_bounds__(256) void scatter_kernel(
    const int* __restrict__ ei_raw, const int* __restrict__ flag,
    const int* __restrict__ row, int* __restrict__ fill, int* __restrict__ esrc)
{
    const int e = blockIdx.x * 256 + threadIdx.x;
    if (e >= ETOT) return;
    int s, d;
    if (e < EE) {
        if (flag[0]) { s = ei_raw[2 * e]; d = ei_raw[2 * (EE + e)]; }
        else         { s = ei_raw[e];     d = ei_raw[EE + e]; }
    } else { s = d = e - EE; }
    const int pos = row[d] + atomicAdd(&fill[d], 1);
    esrc[pos] = s;
}

// ---------------------------------------------------------------------------
// MFMA GEMM with fused f32->bf16 x conversion via LDS staging.
// Block = 256 thr = 4 waves; computes 32 rows x 256 cols (all parts/halves).
// Wave w: part=w>>1, colhalf=w&1 (64 cols, 4 col-tiles), both 16-row groups.
// A from LDS xa[32][136] (pad 8 -> 2-way bank alias, free); B from wbf global.
// C/D: col=lane&15, row=(lane>>4)*4+reg. Epilogue via LDS for 16B stores.
// ---------------------------------------------------------------------------
__global__ __launch_bounds__(256) void gemm_mfma_kernel(
    const float* __restrict__ x, const ushortT* __restrict__ wbf,
    ushortT* __restrict__ xph)
{
    __shared__ ushortT xa[32][136];       // 8.7 KB staging, 272B rows (16B aligned)
    __shared__ ushortT tl[4][32][72];     // 18.4 KB epilogue transpose
    const int t = threadIdx.x;
    const int row0 = blockIdx.x * 32;

    // stage + convert 32 rows of x
    {
        const int r = t >> 3, seg = t & 7;
        const int gr = row0 + r;
        const int gr_c = gr < NN ? gr : NN - 1;
        const float* src = x + (size_t)gr_c * CIN + seg * 16;
        const float4 v0 = *(const float4*)(src);
        const float4 v1 = *(const float4*)(src + 4);
        const float4 v2 = *(const float4*)(src + 8);
        const float4 v3 = *(const float4*)(src + 12);
        bf16x8 o0, o1;
        o0[0] = f2bf(v0.x); o0[1] = f2bf(v0.y); o0[2] = f2bf(v0.z); o0[3] = f2bf(v0.w);
        o0[4] = f2bf(v1.x); o0[5] = f2bf(v1.y); o0[6] = f2bf(v1.z); o0[7] = f2bf(v1.w);
        o1[0] = f2bf(v2.x); o1[1] = f2bf(v2.y); o1[2] = f2bf(v2.z); o1[3] = f2bf(v2.w);
        o1[4] = f2bf(v3.x); o1[5] = f2bf(v3.y); o1[6] = f2bf(v3.z); o1[7] = f2bf(v3.w);
        *(bf16x8*)(&xa[r][seg * 16]) = o0;
        *(bf16x8*)(&xa[r][seg * 16 + 8]) = o1;
    }
    __syncthreads();

    const int w = t >> 6, l = t & 63;
    const int part = w >> 1, ch = w & 1;
    const int rowlo = l & 15, kb = (l >> 4) * 8;

    // A fragments for both row groups, all 4 K-steps
    bf16x8 a[2][4];
    #pragma unroll
    for (int rg = 0; rg < 2; ++rg)
        #pragma unroll
        for (int ks = 0; ks < 4; ++ks)
            a[rg][ks] = *(const bf16x8*)(&xa[rg * 16 + rowlo][ks * 32 + kb]);

    f32x4 acc[2][4] = {};
    const ushortT* wbase = wbf + (size_t)(part * 128 + ch * 64 + rowlo) * 128 + kb;
    #pragma unroll
    for (int ks = 0; ks < 4; ++ks) {
        #pragma unroll
        for (int ct = 0; ct < 4; ++ct) {
            const bf16x8 b = *(const bf16x8*)(wbase + (size_t)ct * 16 * 128 + ks * 32);
            acc[0][ct] = __builtin_amdgcn_mfma_f32_16x16x32_bf16(a[0][ks], b, acc[0][ct], 0, 0, 0);
            acc[1][ct] = __builtin_amdgcn_mfma_f32_16x16x32_bf16(a[1][ks], b, acc[1][ct], 0, 0, 0);
        }
    }

    #pragma unroll
    for (int rg = 0; rg < 2; ++rg)
        #pragma unroll
        for (int ct = 0; ct < 4; ++ct)
            #pragma unroll
            for (int j = 0; j < 4; ++j)
                tl[w][rg * 16 + (l >> 4) * 4 + j][ct * 16 + rowlo] = f2bf(acc[rg][ct][j]);
    __syncthreads();

    // cooperative store: 32 rows x 256 ushorts = 1024 chunks of 8
    #pragma unroll
    for (int c = 0; c < 4; ++c) {
        const int cid = c * 256 + t;
        const int r = cid >> 5, col = (cid & 31) * 8;
        const int gr = row0 + r;
        if (gr < NN)
            *(bf16x8*)(xph + (size_t)gr * 256 + col) =
                *(const bf16x8*)(&tl[col >> 6][r][col & 63]);
    }
}

// ---------------------------------------------------------------------------
// Fused per-node GATv2: one wave per node, lane = h*16+dd covers 2 dims.
// Unrolled 4 edges/iter: 8 independent gathers in flight. No atomics.
// ---------------------------------------------------------------------------
#define EDGE_BODY(sa, sc_out)                                            \
    {                                                                     \
        const uintT ul = *(const uintT*)(xph + (size_t)(sa) * 256 + lane * 2); \
        float vx = bflo(ul) + rnx, vy = bfhi(ul) + rny;                   \
        vx = vx > 0.f ? vx : NEG * vx;                                    \
        vy = vy > 0.f ? vy : NEG * vy;                                    \
        sc_out = vx * a2.x + vy * a2.y;                                   \
    }

__global__ __launch_bounds__(256) void gat_node_kernel(
    const int* __restrict__ row, const int* __restrict__ esrc,
    const ushortT* __restrict__ xph, const float* __restrict__ att,
    const float* __restrict__ bias, float* __restrict__ out)
{
    const int lane = threadIdx.x & 63;
    const int h = lane >> 4, dd = lane & 15;
    const int n = blockIdx.x * 4 + (threadIdx.x >> 6);
    if (n >= NN) return;

    const float2 a2 = *(const float2*)(att + h * DD + dd * 2);
    const uintT urn = *(const uintT*)(xph + (size_t)n * 256 + 128 + lane * 2);
    const float rnx = bflo(urn), rny = bfhi(urn);

    const int p0 = row[n], p1 = row[n + 1];
    float den = 0.f, ax = 0.f, ay = 0.f;
    int p = p0;

    for (; p + 4 <= p1; p += 4) {
        const int s0 = esrc[p], s1 = esrc[p + 1], s2 = esrc[p + 2], s3 = esrc[p + 3];
        const uintT us0 = *(const uintT*)(xph + (size_t)s0 * 256 + 128 + lane * 2);
        const uintT us1 = *(const uintT*)(xph + (size_t)s1 * 256 + 128 + lane * 2);
        const uintT us2 = *(const uintT*)(xph + (size_t)s2 * 256 + 128 + lane * 2);
        const uintT us3 = *(const uintT*)(xph + (size_t)s3 * 256 + 128 + lane * 2);
        float c0, c1, c2, c3;
        EDGE_BODY(s0, c0) EDGE_BODY(s1, c1) EDGE_BODY(s2, c2) EDGE_BODY(s3, c3)
        c0 += __shfl_xor(c0, 1); c1 += __shfl_xor(c1, 1);
        c2 += __shfl_xor(c2, 1); c3 += __shfl_xor(c3, 1);
        c0 += __shfl_xor(c0, 2); c1 += __shfl_xor(c1, 2);
        c2 += __shfl_xor(c2, 2); c3 += __shfl_xor(c3, 2);
        c0 += __shfl_xor(c0, 4); c1 += __shfl_xor(c1, 4);
        c2 += __shfl_xor(c2, 4); c3 += __shfl_xor(c3, 4);
        c0 += __shfl_xor(c0, 8); c1 += __shfl_xor(c1, 8);
        c2 += __shfl_xor(c2, 8); c3 += __shfl_xor(c3, 8);
        const float e0 = __expf(c0), e1 = __expf(c1);
        const float e2 = __expf(c2), e3 = __expf(c3);
        den += (e0 + e1) + (e2 + e3);
        ax = fmaf(e0, bflo(us0), ax); ay = fmaf(e0, bfhi(us0), ay);
        ax = fmaf(e1, bflo(us1), ax); ay = fmaf(e1, bfhi(us1), ay);
        ax = fmaf(e2, bflo(us2), ax); ay = fmaf(e2, bfhi(us2), ay);
        ax = fmaf(e3, bflo(us3), ax); ay = fmaf(e3, bfhi(us3), ay);
    }
    for (; p < p1; ++p) {
        const int s = esrc[p];
        const uintT us = *(const uintT*)(xph + (size_t)s * 256 + 128 + lane * 2);
        float c;
        EDGE_BODY(s, c)
        c += __shfl_xor(c, 1);
        c += __shfl_xor(c, 2);
        c += __shfl_xor(c, 4);
        c += __shfl_xor(c, 8);
        const float pe = __expf(c);
        den += pe;
        ax = fmaf(pe, bflo(us), ax);
        ay = fmaf(pe, bfhi(us), ay);
    }

    const float inv = 1.f / fmaxf(den, 1e-16f);
    ax *= inv; ay *= inv;
    ax += __shfl_xor(ax, 16); ay += __shfl_xor(ay, 16);
    ax += __shfl_xor(ax, 32); ay += __shfl_xor(ay, 32);
    if (h == 0) {
        float2 o;
        o.x = ax * 0.25f + bias[dd * 2];
        o.y = ay * 0.25f + bias[dd * 2 + 1];
        *(float2*)(out + (size_t)n * DD + dd * 2) = o;
    }
}

extern "C" void kernel_launch(void* const* d_in, const int* in_sizes, int n_in,
                              void* d_out, int out_size, void* d_ws, size_t ws_size,
                              hipStream_t stream)
{
    const float* x    = (const float*)d_in[0];
    const int*   ei   = (const int*)d_in[1];
    const float* Wl   = (const float*)d_in[2];
    const float* Wr   = (const float*)d_in[3];
    const float* att  = (const float*)d_in[4];
    const float* bias = (const float*)d_in[5];
    float* out = (float*)d_out;

    float*   ws   = (float*)d_ws;
    int*     flag = (int*)ws;
    int*     cnt  = (int*)(ws + CNT_OFF);
    int*     fill = (int*)(ws + FILL_OFF);
    int*     row  = (int*)(ws + ROW_OFF);
    int*     esrc = (int*)(ws + ESRC_OFF);
    int*     btot = (int*)(ws + BTOT_OFF);
    ushortT* wbf  = (ushortT*)(ws + WBF_OFF);
    ushortT* xph  = (ushortT*)(ws + XPH_OFF);

    // zero cnt + fill (contiguous 400 KB)
    hipMemsetAsync(cnt, 0, (size_t)(2 * NN) * sizeof(int), stream);

    hipLaunchKernelGGL(detect_kernel, dim3(1), dim3(64), 0, stream, ei, flag);
    hipLaunchKernelGGL(hist_kernel, dim3((EE + 255) / 256), dim3(256), 0, stream,
                       ei, flag, cnt);
    hipLaunchKernelGGL(wprep_kernel, dim3(16), dim3(256), 0, stream, Wl, Wr, wbf);
    hipLaunchKernelGGL(scan1_kernel, dim3(SCAN_NB), dim3(1024), 0, stream, cnt, row, btot);
    hipLaunchKernelGGL(scan3_kernel, dim3((NN + 256) / 256), dim3(256), 0, stream, row, btot);
    hipLaunchKernelGGL(scatter_kernel, dim3((ETOT + 255) / 256), dim3(256), 0, stream,
                       ei, flag, row, fill, esrc);
    hipLaunchKernelGGL(gemm_mfma_kernel, dim3((NN + 31) / 32), dim3(256), 0, stream,
                       x, wbf, xph);
    hipLaunchKernelGGL(gat_node_kernel, dim3((NN + 3) / 4), dim3(256), 0, stream,
                       row, esrc, xph, att, bias, out);
}

// Round 12
// 183.531 us; speedup vs baseline: 2.5623x; 1.0356x over previous
//
#include <hip/hip_runtime.h>
#include <hip/hip_bf16.h>

#define NN 50000
#define CIN 128
#define HH 4
#define DD 32
#define HD 128
#define EE 800000
#define NEG 0.2f

typedef unsigned short ushortT;
typedef unsigned int uintT;
typedef __attribute__((ext_vector_type(8))) short bf16x8;
typedef __attribute__((ext_vector_type(4))) float f32x4;

// ---------------------------------------------------------------------------
// ws layout (units of 4B):
//   [0]       : flag (1 = edge_index is int64, 0 = int32)
//   CNT_OFF  = 16       : per-node in-degree (excl self) (NN ints) [memset 0]
//   FILL_OFF = 50016    : scatter fill counters (NN ints)          [memset 0]
//   ROW_OFF  = 100032   : CSR row offsets (NN+1 ints)
//   ESRC_OFF = 150048   : dst-sorted src indices (EE ints)
//   BTOT_OFF = 1000048  : scan block totals (64 ints)
//   WBF_OFF  = 1000112  : W bf16 [256][128] (16384 float-slots)
//   XPH_OFF  = 1016496  : interleaved bf16 rows xl|xr [NN][256] (3.2M slots)
// total 4,216,496 floats = 16.9 MB
// ---------------------------------------------------------------------------
#define CNT_OFF  16
#define FILL_OFF 50016
#define ROW_OFF  100032
#define ESRC_OFF 150048
#define BTOT_OFF 1000048
#define WBF_OFF  1000112
#define XPH_OFF  1016496
#define SCAN_NB  49          // ceil((NN+1)/1024)

__device__ __forceinline__ ushortT f2bf(float f) {
    uintT u = __float_as_uint(f);
    u = (u + 0x7fff + ((u >> 16) & 1)) >> 16;   // RNE
    return (ushortT)u;
}
__device__ __forceinline__ float bflo(uintT u) { return __uint_as_float(u << 16); }
__device__ __forceinline__ float bfhi(uintT u) { return __uint_as_float(u & 0xffff0000u); }

// ---------------------------------------------------------------------------
// Detect int64 vs int32 edge_index: int64 values < 2^31 have zero odd words.
// ---------------------------------------------------------------------------
__global__ void detect_kernel(const int* __restrict__ ei_raw, int* __restrict__ flag)
{
    const int l = threadIdx.x;                // 64 threads
    const int w = ei_raw[2 * l + 1];
    const unsigned long long b = __ballot(w != 0);
    if (l == 0) flag[0] = (b == 0ULL) ? 1 : 0;
}

// histogram dst straight from raw edge index; 4 edges/thread (grid-stride)
__global__ __launch_bounds__(256) void hist_kernel(
    const int* __restrict__ ei_raw, const int* __restrict__ flag, int* __restrict__ cnt)
{
    const int t0 = blockIdx.x * 256 + threadIdx.x;
    const int stride = gridDim.x * 256;
    const int f = flag[0];
    #pragma unroll
    for (int k = 0; k < 4; ++k) {
        const int e = t0 + k * stride;
        if (e < EE) {
            const int d = f ? ei_raw[2 * (EE + e)] : ei_raw[EE + e];
            atomicAdd(&cnt[d], 1);
        }
    }
}

// convert Wl|Wr to bf16: wbf[256][128], rows 0..127 = Wl, 128..255 = Wr
__global__ __launch_bounds__(256) void wprep_kernel(
    const float* __restrict__ Wl, const float* __restrict__ Wr, ushortT* __restrict__ wbf)
{
    const int i = blockIdx.x * 256 + threadIdx.x;   // 4096 threads, 8 elems each
    const float* src = (i < 2048) ? Wl : Wr;
    const int off = (i < 2048) ? i : i - 2048;
    const float4 v0 = *(const float4*)(src + (size_t)off * 8);
    const float4 v1 = *(const float4*)(src + (size_t)off * 8 + 4);
    bf16x8 o;
    o[0] = f2bf(v0.x); o[1] = f2bf(v0.y); o[2] = f2bf(v0.z); o[3] = f2bf(v0.w);
    o[4] = f2bf(v1.x); o[5] = f2bf(v1.y); o[6] = f2bf(v1.z); o[7] = f2bf(v1.w);
    *(bf16x8*)(wbf + ((i < 2048) ? 0 : 16384) + (size_t)off * 8) = o;
}

// ---------------------------------------------------------------------------
// scan1: block-local exclusive scan of cnt (self-loops handled inline later)
// ---------------------------------------------------------------------------
__global__ __launch_bounds__(1024) void scan1_kernel(
    const int* __restrict__ cnt, int* __restrict__ row, int* __restrict__ btot)
{
    __shared__ int wtot[16];
    const int t = threadIdx.x, lane = t & 63, wv = t >> 6;
    const int i = blockIdx.x * 1024 + t;
    const int v = (i < NN) ? cnt[i] : 0;
    int acc = v;
    #pragma unroll
    for (int off = 1; off < 64; off <<= 1) {
        const int u = __shfl_up(acc, off, 64);
        if (lane >= off) acc += u;
    }
    if (lane == 63) wtot[wv] = acc;
    __syncthreads();
    if (wv == 0 && lane < 16) {
        const int wvv = wtot[lane];
        int wacc = wvv;
        #pragma unroll
        for (int off = 1; off < 16; off <<= 1) {
            const int u = __shfl_up(wacc, off, 64);
            if (lane >= off) wacc += u;
        }
        wtot[lane] = wacc - wvv;            // exclusive wave offset
    }
    __syncthreads();
    const int ex = wtot[wv] + acc - v;      // block-local exclusive prefix
    if (i <= NN) row[i] = ex;
    if (t == 1023) btot[blockIdx.x] = ex + v;
}

// scan3: each block wave-reduces its own btot prefix, adds to row
__global__ __launch_bounds__(256) void scan3_kernel(
    int* __restrict__ row, const int* __restrict__ btot)
{
    const int i = blockIdx.x * 256 + threadIdx.x;
    const int chunk = blockIdx.x >> 2;              // 1024-chunk id (const per block)
    const int lane = threadIdx.x & 63;
    int v = (lane < chunk) ? btot[lane] : 0;
    #pragma unroll
    for (int off = 1; off < 64; off <<= 1) v += __shfl_xor(v, off);
    if (i <= NN) row[i] += v;
}

// place src of each real edge into its dst segment; 4 edges/thread
__global__ __launch_bounds__(256) void scatter_kernel(
    const int* __restrict__ ei_raw, const int* __restrict__ flag,
    const int* __restrict__ row, int* __restrict__ fill, int* __restrict__ esrc)
{
    const int t0 = blockIdx.x * 256 + threadIdx.x;
    const int stride = gridDim.x * 256;
    const int f = flag[0];
    #pragma unroll
    for (int k = 0; k < 4; ++k) {
        const int e = t0 + k * stride;
        if (e < EE) {
            int s, d;
            if (f) { s = ei_raw[2 * e]; d = ei_raw[2 * (EE + e)]; }
            else   { s = ei_raw[e];     d = ei_raw[EE + e]; }
            const int pos = row[d] + atomicAdd(&fill[d], 1);
            esrc[pos] = s;
        }
    }
}

// ---------------------------------------------------------------------------
// MFMA GEMM with fused f32->bf16 x conversion via LDS staging.
// Block = 256 thr = 4 waves; computes 32 rows x 256 cols (all parts/halves).
// ---------------------------------------------------------------------------
__global__ __launch_bounds__(256) void gemm_mfma_kernel(
    const float* __restrict__ x, const ushortT* __restrict__ wbf,
    ushortT* __restrict__ xph)
{
    __shared__ ushortT xa[32][136];       // 8.7 KB staging, 272B rows (16B aligned)
    __shared__ ushortT tl[4][32][72];     // 18.4 KB epilogue transpose
    const int t = threadIdx.x;
    const int row0 = blockIdx.x * 32;

    // stage + convert 32 rows of x
    {
        const int r = t >> 3, seg = t & 7;
        const int gr = row0 + r;
        const int gr_c = gr < NN ? gr : NN - 1;
        const float* src = x + (size_t)gr_c * CIN + seg * 16;
        const float4 v0 = *(const float4*)(src);
        const float4 v1 = *(const float4*)(src + 4);
        const float4 v2 = *(const float4*)(src + 8);
        const float4 v3 = *(const float4*)(src + 12);
        bf16x8 o0, o1;
        o0[0] = f2bf(v0.x); o0[1] = f2bf(v0.y); o0[2] = f2bf(v0.z); o0[3] = f2bf(v0.w);
        o0[4] = f2bf(v1.x); o0[5] = f2bf(v1.y); o0[6] = f2bf(v1.z); o0[7] = f2bf(v1.w);
        o1[0] = f2bf(v2.x); o1[1] = f2bf(v2.y); o1[2] = f2bf(v2.z); o1[3] = f2bf(v2.w);
        o1[4] = f2bf(v3.x); o1[5] = f2bf(v3.y); o1[6] = f2bf(v3.z); o1[7] = f2bf(v3.w);
        *(bf16x8*)(&xa[r][seg * 16]) = o0;
        *(bf16x8*)(&xa[r][seg * 16 + 8]) = o1;
    }
    __syncthreads();

    const int w = t >> 6, l = t & 63;
    const int part = w >> 1, ch = w & 1;
    const int rowlo = l & 15, kb = (l >> 4) * 8;

    bf16x8 a[2][4];
    #pragma unroll
    for (int rg = 0; rg < 2; ++rg)
        #pragma unroll
        for (int ks = 0; ks < 4; ++ks)
            a[rg][ks] = *(const bf16x8*)(&xa[rg * 16 + rowlo][ks * 32 + kb]);

    f32x4 acc[2][4] = {};
    const ushortT* wbase = wbf + (size_t)(part * 128 + ch * 64 + rowlo) * 128 + kb;
    #pragma unroll
    for (int ks = 0; ks < 4; ++ks) {
        #pragma unroll
        for (int ct = 0; ct < 4; ++ct) {
            const bf16x8 b = *(const bf16x8*)(wbase + (size_t)ct * 16 * 128 + ks * 32);
            acc[0][ct] = __builtin_amdgcn_mfma_f32_16x16x32_bf16(a[0][ks], b, acc[0][ct], 0, 0, 0);
            acc[1][ct] = __builtin_amdgcn_mfma_f32_16x16x32_bf16(a[1][ks], b, acc[1][ct], 0, 0, 0);
        }
    }

    #pragma unroll
    for (int rg = 0; rg < 2; ++rg)
        #pragma unroll
        for (int ct = 0; ct < 4; ++ct)
            #pragma unroll
            for (int j = 0; j < 4; ++j)
                tl[w][rg * 16 + (l >> 4) * 4 + j][ct * 16 + rowlo] = f2bf(acc[rg][ct][j]);
    __syncthreads();

    #pragma unroll
    for (int c = 0; c < 4; ++c) {
        const int cid = c * 256 + t;
        const int r = cid >> 5, col = (cid & 31) * 8;
        const int gr = row0 + r;
        if (gr < NN)
            *(bf16x8*)(xph + (size_t)gr * 256 + col) =
                *(const bf16x8*)(&tl[col >> 6][r][col & 63]);
    }
}

// ---------------------------------------------------------------------------
// Fused per-node GATv2: one wave per node, lane = h*16+dd covers 2 dims.
// Self-loop computed inline (not in CSR). Unrolled 8 edges/iter:
// 8 esrc + 16 row-gathers issued up front, processed in two 4-groups.
// ---------------------------------------------------------------------------
#define SCORE_OF(ulv, cv)                                                 \
    {                                                                     \
        float vx = bflo(ulv) + rnx, vy = bfhi(ulv) + rny;                 \
        vx = vx > 0.f ? vx : NEG * vx;                                    \
        vy = vy > 0.f ? vy : NEG * vy;                                    \
        cv = vx * a2.x + vy * a2.y;                                       \
    }
#define RED16(cv)                                                         \
    cv += __shfl_xor(cv, 1); cv += __shfl_xor(cv, 2);                     \
    cv += __shfl_xor(cv, 4); cv += __shfl_xor(cv, 8);

__global__ __launch_bounds__(256) void gat_node_kernel(
    const int* __restrict__ row, const int* __restrict__ esrc,
    const ushortT* __restrict__ xph, const float* __restrict__ att,
    const float* __restrict__ bias, float* __restrict__ out)
{
    const int lane = threadIdx.x & 63;
    const int h = lane >> 4, dd = lane & 15;
    const int n = blockIdx.x * 4 + (threadIdx.x >> 6);
    if (n >= NN) return;

    const float2 a2 = *(const float2*)(att + h * DD + dd * 2);
    const uintT uln = *(const uintT*)(xph + (size_t)n * 256 + lane * 2);
    const uintT urn = *(const uintT*)(xph + (size_t)n * 256 + 128 + lane * 2);
    const float rnx = bflo(urn), rny = bfhi(urn);

    // self-loop first
    float den, ax, ay;
    {
        float c;
        SCORE_OF(uln, c)
        RED16(c)
        const float pe = __expf(c);
        den = pe;
        ax = pe * bflo(urn);
        ay = pe * bfhi(urn);
    }

    const int p0 = row[n], p1 = row[n + 1];
    int p = p0;

    for (; p + 8 <= p1; p += 8) {
        int s[8];
        #pragma unroll
        for (int j = 0; j < 8; ++j) s[j] = esrc[p + j];
        uintT ul[8], us[8];
        #pragma unroll
        for (int j = 0; j < 8; ++j) {
            ul[j] = *(const uintT*)(xph + (size_t)s[j] * 256 + lane * 2);
            us[j] = *(const uintT*)(xph + (size_t)s[j] * 256 + 128 + lane * 2);
        }
        #pragma unroll
        for (int g = 0; g < 2; ++g) {
            float c0, c1, c2, c3;
            SCORE_OF(ul[g * 4 + 0], c0) SCORE_OF(ul[g * 4 + 1], c1)
            SCORE_OF(ul[g * 4 + 2], c2) SCORE_OF(ul[g * 4 + 3], c3)
            c0 += __shfl_xor(c0, 1); c1 += __shfl_xor(c1, 1);
            c2 += __shfl_xor(c2, 1); c3 += __shfl_xor(c3, 1);
            c0 += __shfl_xor(c0, 2); c1 += __shfl_xor(c1, 2);
            c2 += __shfl_xor(c2, 2); c3 += __shfl_xor(c3, 2);
            c0 += __shfl_xor(c0, 4); c1 += __shfl_xor(c1, 4);
            c2 += __shfl_xor(c2, 4); c3 += __shfl_xor(c3, 4);
            c0 += __shfl_xor(c0, 8); c1 += __shfl_xor(c1, 8);
            c2 += __shfl_xor(c2, 8); c3 += __shfl_xor(c3, 8);
            const float e0 = __expf(c0), e1 = __expf(c1);
            const float e2 = __expf(c2), e3 = __expf(c3);
            den += (e0 + e1) + (e2 + e3);
            ax = fmaf(e0, bflo(us[g * 4 + 0]), ax); ay = fmaf(e0, bfhi(us[g * 4 + 0]), ay);
            ax = fmaf(e1, bflo(us[g * 4 + 1]), ax); ay = fmaf(e1, bfhi(us[g * 4 + 1]), ay);
            ax = fmaf(e2, bflo(us[g * 4 + 2]), ax); ay = fmaf(e2, bfhi(us[g * 4 + 2]), ay);
            ax = fmaf(e3, bflo(us[g * 4 + 3]), ax); ay = fmaf(e3, bfhi(us[g * 4 + 3]), ay);
        }
    }
    for (; p + 4 <= p1; p += 4) {
        int s[4];
        #pragma unroll
        for (int j = 0; j < 4; ++j) s[j] = esrc[p + j];
        uintT ul[4], us[4];
        #pragma unroll
        for (int j = 0; j < 4; ++j) {
            ul[j] = *(const uintT*)(xph + (size_t)s[j] * 256 + lane * 2);
            us[j] = *(const uintT*)(xph + (size_t)s[j] * 256 + 128 + lane * 2);
        }
        float c0, c1, c2, c3;
        SCORE_OF(ul[0], c0) SCORE_OF(ul[1], c1) SCORE_OF(ul[2], c2) SCORE_OF(ul[3], c3)
        c0 += __shfl_xor(c0, 1); c1 += __shfl_xor(c1, 1);
        c2 += __shfl_xor(c2, 1); c3 += __shfl_xor(c3, 1);
        c0 += __shfl_xor(c0, 2); c1 += __shfl_xor(c1, 2);
        c2 += __shfl_xor(c2, 2); c3 += __shfl_xor(c3, 2);
        c0 += __shfl_xor(c0, 4); c1 += __shfl_xor(c1, 4);
        c2 += __shfl_xor(c2, 4); c3 += __shfl_xor(c3, 4);
        c0 += __shfl_xor(c0, 8); c1 += __shfl_xor(c1, 8);
        c2 += __shfl_xor(c2, 8); c3 += __shfl_xor(c3, 8);
        const float e0 = __expf(c0), e1 = __expf(c1);
        const float e2 = __expf(c2), e3 = __expf(c3);
        den += (e0 + e1) + (e2 + e3);
        ax = fmaf(e0, bflo(us[0]), ax); ay = fmaf(e0, bfhi(us[0]), ay);
        ax = fmaf(e1, bflo(us[1]), ax); ay = fmaf(e1, bfhi(us[1]), ay);
        ax = fmaf(e2, bflo(us[2]), ax); ay = fmaf(e2, bfhi(us[2]), ay);
        ax = fmaf(e3, bflo(us[3]), ax); ay = fmaf(e3, bfhi(us[3]), ay);
    }
    for (; p < p1; ++p) {
        const int s = esrc[p];
        const uintT ul = *(const uintT*)(xph + (size_t)s * 256 + lane * 2);
        const uintT us = *(const uintT*)(xph + (size_t)s * 256 + 128 + lane * 2);
        float c;
        SCORE_OF(ul, c)
        RED16(c)
        const float pe = __expf(c);
        den += pe;
        ax = fmaf(pe, bflo(us), ax);
        ay = fmaf(pe, bfhi(us), ay);
    }

    const float inv = 1.f / fmaxf(den, 1e-16f);
    ax *= inv; ay *= inv;
    ax += __shfl_xor(ax, 16); ay += __shfl_xor(ay, 16);
    ax += __shfl_xor(ax, 32); ay += __shfl_xor(ay, 32);
    if (h == 0) {
        float2 o;
        o.x = ax * 0.25f + bias[dd * 2];
        o.y = ay * 0.25f + bias[dd * 2 + 1];
        *(float2*)(out + (size_t)n * DD + dd * 2) = o;
    }
}

extern "C" void kernel_launch(void* const* d_in, const int* in_sizes, int n_in,
                              void* d_out, int out_size, void* d_ws, size_t ws_size,
                              hipStream_t stream)
{
    const float* x    = (const float*)d_in[0];
    const int*   ei   = (const int*)d_in[1];
    const float* Wl   = (const float*)d_in[2];
    const float* Wr   = (const float*)d_in[3];
    const float* att  = (const float*)d_in[4];
    const float* bias = (const float*)d_in[5];
    float* out = (float*)d_out;

    float*   ws   = (float*)d_ws;
    int*     flag = (int*)ws;
    int*     cnt  = (int*)(ws + CNT_OFF);
    int*     fill = (int*)(ws + FILL_OFF);
    int*     row  = (int*)(ws + ROW_OFF);
    int*     esrc = (int*)(ws + ESRC_OFF);
    int*     btot = (int*)(ws + BTOT_OFF);
    ushortT* wbf  = (ushortT*)(ws + WBF_OFF);
    ushortT* xph  = (ushortT*)(ws + XPH_OFF);

    // zero cnt + fill (contiguous 400 KB)
    hipMemsetAsync(cnt, 0, (size_t)(2 * NN) * sizeof(int), stream);

    hipLaunchKernelGGL(detect_kernel, dim3(1), dim3(64), 0, stream, ei, flag);
    hipLaunchKernelGGL(hist_kernel, dim3((EE + 1023) / 1024), dim3(256), 0, stream,
                       ei, flag, cnt);
    hipLaunchKernelGGL(wprep_kernel, dim3(16), dim3(256), 0, stream, Wl, Wr, wbf);
    hipLaunchKernelGGL(scan1_kernel, dim3(SCAN_NB), dim3(1024), 0, stream, cnt, row, btot);
    hipLaunchKernelGGL(scan3_kernel, dim3((NN + 256) / 256), dim3(256), 0, stream, row, btot);
    hipLaunchKernelGGL(scatter_kernel, dim3((EE + 1023) / 1024), dim3(256), 0, stream,
                       ei, flag, row, fill, esrc);
    hipLaunchKernelGGL(gemm_mfma_kernel, dim3((NN + 31) / 32), dim3(256), 0, stream,
                       x, wbf, xph);
    hipLaunchKernelGGL(gat_node_kernel, dim3((NN + 3) / 4), dim3(256), 0, stream,
                       row, esrc, xph, att, bias, out);
}